// Round 1
// baseline (1389.607 us; speedup 1.0000x reference)
//
#include <hip/hip_runtime.h>
#include <math.h>

#define N_    4096
#define W_    7
#define NPAIR (N_ * W_)   // 28672
#define TS    20          // transposed LDS row stride (16 n + pad)

__device__ __forceinline__ float sigm(float x) { return 1.0f / (1.0f + __expf(-x)); }
__device__ __forceinline__ float tanh_fast(float x) { return 2.0f / (1.0f + __expf(-2.0f * x)) - 1.0f; }

// ---------------- K1: weighted neighbor reduction + msg/lin matvecs ----------------
// grid = NPAIR/16 = 1792 blocks, 256 threads (4 waves, 4 pairs each)
__global__ __launch_bounds__(256) void k1_msg(
    const float* __restrict__ X, const float* __restrict__ C,
    const float* __restrict__ msg_W, const float* __restrict__ msg_b,
    const float* __restrict__ lin_W, const float* __restrict__ lin_b,
    float* __restrict__ hmsg, float* __restrict__ hself)
{
  __shared__ float s_xw[16][260];
  __shared__ float s_tx[16][260];
  __shared__ float s_ps[16];
  const int tid = threadIdx.x;
  const int wave = tid >> 6, lane = tid & 63;
  const int p0 = blockIdx.x * 16;

  for (int q = 0; q < 4; ++q) {
    const int lp = wave * 4 + q;
    const int p = p0 + lp;
    const int n = p / 7, w = p - n * 7;
    const float* xb = X + ((size_t)(n * 33 + 1) * 7 + w) * 256 + lane * 4;
    const float* cb = C + (size_t)(n * 33 + 1) * 7 + w;
    float4 acc = make_float4(0.f, 0.f, 0.f, 0.f);
    float ps = 0.f;
    #pragma unroll 4
    for (int m = 0; m < 32; ++m) {
      const float c = cb[m * 7];
      const float4 x4 = *(const float4*)(xb + (size_t)m * 1792);
      acc.x += c * x4.x; acc.y += c * x4.y; acc.z += c * x4.z; acc.w += c * x4.w;
      ps += c;
    }
    *(float4*)&s_xw[lp][lane * 4] = acc;
    const float4 t4 = *(const float4*)(X + ((size_t)(n * 33) * 7 + w) * 256 + lane * 4);
    *(float4*)&s_tx[lp][lane * 4] = t4;
    if (lane == 0) s_ps[lp] = ps;
  }
  __syncthreads();

  const int r = tid & 127, nh = tid >> 7;
  float accm[8], accs[8];
  const float mb = msg_b[r], lb = lin_b[r];
  #pragma unroll
  for (int j = 0; j < 8; ++j) { accm[j] = mb * s_ps[nh * 8 + j]; accs[j] = lb; }
  const float4* wm4 = (const float4*)(msg_W + (size_t)r * 256);
  const float4* wl4 = (const float4*)(lin_W + (size_t)r * 256);
  for (int k4 = 0; k4 < 64; ++k4) {
    const float4 wm = wm4[k4];
    const float4 wl = wl4[k4];
    #pragma unroll
    for (int j = 0; j < 8; ++j) {
      const float4 xa = *(const float4*)&s_xw[nh * 8 + j][k4 * 4];
      const float4 ta = *(const float4*)&s_tx[nh * 8 + j][k4 * 4];
      accm[j] += wm.x * xa.x + wm.y * xa.y + wm.z * xa.z + wm.w * xa.w;
      accs[j] += wl.x * ta.x + wl.y * ta.y + wl.z * ta.z + wl.w * ta.w;
    }
  }
  #pragma unroll
  for (int j = 0; j < 8; ++j) {
    const int p = p0 + nh * 8 + j;
    hmsg[(size_t)p * 128 + r] = accm[j];
    hself[(size_t)p * 128 + r] = accs[j];
  }
}

// ---------------- K2: sequential chain (gru0 -> gru1 -> lin2 -> cell gru -> head) ---
// one block = 16 n's; LDS state transposed [feature][n]
__device__ __forceinline__ void gru_core(
    const float (*__restrict__ in)[TS], float (*__restrict__ h)[TS],
    float (*__restrict__ hout)[TS],
    const float* __restrict__ Wih, const float* __restrict__ Whh,
    const float* __restrict__ bih, const float* __restrict__ bhh,
    const int d, const int ih)
{
  const int ih8 = ih * 8;
  const float4* wiR = (const float4*)(Wih + (size_t)d * 128);
  const float4* wiZ = (const float4*)(Wih + (size_t)(d + 128) * 128);
  const float4* wiN = (const float4*)(Wih + (size_t)(d + 256) * 128);
  const float4* whR = (const float4*)(Whh + (size_t)d * 128);
  const float4* whZ = (const float4*)(Whh + (size_t)(d + 128) * 128);
  const float4* whN = (const float4*)(Whh + (size_t)(d + 256) * 128);
  float aR[8], aZ[8], aN[8], aH[8];
  const float bR = bih[d] + bhh[d];
  const float bZ = bih[d + 128] + bhh[d + 128];
  const float bXN = bih[d + 256], bHN = bhh[d + 256];
  #pragma unroll
  for (int j = 0; j < 8; ++j) { aR[j] = bR; aZ[j] = bZ; aN[j] = bXN; aH[j] = bHN; }

  for (int k4 = 0; k4 < 32; ++k4) {
    const float4 wir = wiR[k4], wiz = wiZ[k4], win = wiN[k4];
    const float4 whr = whR[k4], whz = whZ[k4], whn = whN[k4];
    #pragma unroll
    for (int kk = 0; kk < 4; ++kk) {
      const int k = k4 * 4 + kk;
      const float4 ia = *(const float4*)&in[k][ih8];
      const float4 ib = *(const float4*)&in[k][ih8 + 4];
      const float4 ha = *(const float4*)&h[k][ih8];
      const float4 hb = *(const float4*)&h[k][ih8 + 4];
      const float iv[8] = {ia.x, ia.y, ia.z, ia.w, ib.x, ib.y, ib.z, ib.w};
      const float hv[8] = {ha.x, ha.y, ha.z, ha.w, hb.x, hb.y, hb.z, hb.w};
      const float wi_r = ((const float*)&wir)[kk];
      const float wi_z = ((const float*)&wiz)[kk];
      const float wi_n = ((const float*)&win)[kk];
      const float wh_r = ((const float*)&whr)[kk];
      const float wh_z = ((const float*)&whz)[kk];
      const float wh_n = ((const float*)&whn)[kk];
      #pragma unroll
      for (int j = 0; j < 8; ++j) {
        aR[j] += wi_r * iv[j] + wh_r * hv[j];
        aZ[j] += wi_z * iv[j] + wh_z * hv[j];
        aN[j] += wi_n * iv[j];
        aH[j] += wh_n * hv[j];
      }
    }
  }
  __syncthreads();  // all matvec reads done before state writes
  #pragma unroll
  for (int j = 0; j < 8; ++j) {
    const int n = ih8 + j;
    const float rr = sigm(aR[j]);
    const float zz = sigm(aZ[j]);
    const float nn = tanh_fast(aN[j] + rr * aH[j]);
    hout[d][n] = (1.f - zz) * nn + zz * h[d][n];
  }
  __syncthreads();
}

__global__ __launch_bounds__(256) void k2_chain(
    const float* __restrict__ hmsg, const float* __restrict__ hself,
    const float* __restrict__ Y,
    const float* __restrict__ g0_Wih, const float* __restrict__ g0_Whh,
    const float* __restrict__ g0_bih, const float* __restrict__ g0_bhh,
    const float* __restrict__ g1_Wih, const float* __restrict__ g1_Whh,
    const float* __restrict__ g1_bih, const float* __restrict__ g1_bhh,
    const float* __restrict__ lin2_W, const float* __restrict__ lin2_b,
    const float* __restrict__ c_Wih, const float* __restrict__ c_Whh,
    const float* __restrict__ c_bih, const float* __restrict__ c_bhh,
    const float* __restrict__ hyp_W, const float* __restrict__ hyp_b,
    const float* __restrict__ bn_gamma, const float* __restrict__ bn_beta,
    const float* __restrict__ bn_mean, const float* __restrict__ bn_var,
    const float* __restrict__ out_W, const float* __restrict__ out_b,
    float* __restrict__ out, float* __restrict__ bloss)
{
  __shared__ float s_h0[128][TS];
  __shared__ float s_h1[128][TS];
  __shared__ float s_hx[128][TS];
  __shared__ float s_in[128][TS];
  __shared__ float s_hs[128][TS];
  __shared__ float s_ls[16];
  const int tid = threadIdx.x;
  const int d = tid & 127, ih = tid >> 7;
  const int ih8 = ih * 8;
  const int n0 = blockIdx.x * 16;

  #pragma unroll
  for (int j = 0; j < 8; ++j) {
    s_h0[d][ih8 + j] = 0.f; s_h1[d][ih8 + j] = 0.f; s_hx[d][ih8 + j] = 0.f;
  }

  for (int w = 0; w < 7; ++w) {
    __syncthreads();  // protect restage vs prior-step reads (and initial zeros)
    #pragma unroll
    for (int j = 0; j < 8; ++j) {
      const int n = ih8 + j;
      const size_t g = (size_t)(n0 + n) * 896 + (size_t)w * 128 + d;
      s_in[d][n] = hmsg[g];
      s_hs[d][n] = hself[g];
    }
    __syncthreads();

    gru_core(s_in, s_h0, s_h0, g0_Wih, g0_Whh, g0_bih, g0_bhh, d, ih);  // gru0
    gru_core(s_h0, s_h1, s_h1, g1_Wih, g1_Whh, g1_bih, g1_bhh, d, ih);  // gru1

    // lin2: hx1 = tanh(W2[:, :128] @ hx + W2[:, 128:] @ h1 + b2)
    float hx1r[8];
    {
      const float4* w2 = (const float4*)(lin2_W + (size_t)d * 256);
      float a2[8];
      const float b2 = lin2_b[d];
      #pragma unroll
      for (int j = 0; j < 8; ++j) a2[j] = b2;
      for (int k4 = 0; k4 < 64; ++k4) {
        const float4 wv = w2[k4];
        #pragma unroll
        for (int kk = 0; kk < 4; ++kk) {
          const int k = k4 * 4 + kk;
          const float (*src)[TS] = (k < 128) ? s_hx : s_h1;
          const int ks = k & 127;
          const float4 xa = *(const float4*)&src[ks][ih8];
          const float4 xb = *(const float4*)&src[ks][ih8 + 4];
          const float xv[8] = {xa.x, xa.y, xa.z, xa.w, xb.x, xb.y, xb.z, xb.w};
          const float wk = ((const float*)&wv)[kk];
          #pragma unroll
          for (int j = 0; j < 8; ++j) a2[j] += wk * xv[j];
        }
      }
      #pragma unroll
      for (int j = 0; j < 8; ++j) hx1r[j] = tanh_fast(a2[j]);
    }
    // safe: all s_in readers (gru0 matvec) finished behind gru0's internal barrier
    #pragma unroll
    for (int j = 0; j < 8; ++j) s_in[d][ih8 + j] = hx1r[j];
    __syncthreads();

    // cell GRU: xg from h_self, recurrent state = hx1 (s_in), result -> s_hx
    gru_core(s_hs, s_in, s_hx, c_Wih, c_Whh, c_bih, c_bhh, d, ih);
  }

  // head: h0 = relu(BN(hyp_W @ hx + hyp_b)); y = out_W @ h0 + out_b
  {
    const float4* wh4 = (const float4*)(hyp_W + (size_t)d * 128);
    float ah[8];
    const float bh = hyp_b[d];
    #pragma unroll
    for (int j = 0; j < 8; ++j) ah[j] = bh;
    for (int k4 = 0; k4 < 32; ++k4) {
      const float4 wv = wh4[k4];
      #pragma unroll
      for (int kk = 0; kk < 4; ++kk) {
        const int k = k4 * 4 + kk;
        const float4 xa = *(const float4*)&s_hx[k][ih8];
        const float4 xb = *(const float4*)&s_hx[k][ih8 + 4];
        const float xv[8] = {xa.x, xa.y, xa.z, xa.w, xb.x, xb.y, xb.z, xb.w};
        const float wk = ((const float*)&wv)[kk];
        #pragma unroll
        for (int j = 0; j < 8; ++j) ah[j] += wk * xv[j];
      }
    }
    const float sc = rsqrtf(bn_var[d] + 1e-5f) * bn_gamma[d];
    const float mu = bn_mean[d], be = bn_beta[d];
    __syncthreads();  // all s_hx reads done; s_in free (cell matvec behind barrier)
    #pragma unroll
    for (int j = 0; j < 8; ++j) {
      const float v = (ah[j] - mu) * sc + be;
      s_in[d][ih8 + j] = fmaxf(v, 0.f);
    }
  }
  __syncthreads();
  if (tid < 16) {
    const int n = tid;
    float y = out_b[0];
    for (int j = 0; j < 128; ++j) y += out_W[j] * s_in[j][n];
    out[1 + n0 + n] = 1.f / (1.f + __expf(-y));
    const float tY = Y[(size_t)(n0 + n) * 33];
    s_ls[n] = fmaxf(y, 0.f) - y * tY + log1pf(__expf(-fabsf(y)));
  }
  __syncthreads();
  if (tid == 0) {
    float s = 0.f;
    #pragma unroll
    for (int j = 0; j < 16; ++j) s += s_ls[j];
    bloss[blockIdx.x] = s;
  }
}

// ---------------- K3: loss reduction ----------------
__global__ __launch_bounds__(256) void k3_loss(const float* __restrict__ bloss,
                                               float* __restrict__ out)
{
  __shared__ float s[256];
  s[threadIdx.x] = bloss[threadIdx.x];
  __syncthreads();
  for (int off = 128; off > 0; off >>= 1) {
    if (threadIdx.x < off) s[threadIdx.x] += s[threadIdx.x + off];
    __syncthreads();
  }
  if (threadIdx.x == 0) out[0] = s[0] * (1.0f / 4096.0f);
}

extern "C" void kernel_launch(void* const* d_in, const int* in_sizes, int n_in,
                              void* d_out, int out_size, void* d_ws, size_t ws_size,
                              hipStream_t stream) {
  const float* X       = (const float*)d_in[0];
  const float* Y       = (const float*)d_in[1];
  const float* C       = (const float*)d_in[2];
  const float* msg_W   = (const float*)d_in[3];
  const float* msg_b   = (const float*)d_in[4];
  const float* g0_Wih  = (const float*)d_in[5];
  const float* g0_Whh  = (const float*)d_in[6];
  const float* g0_bih  = (const float*)d_in[7];
  const float* g0_bhh  = (const float*)d_in[8];
  const float* g1_Wih  = (const float*)d_in[9];
  const float* g1_Whh  = (const float*)d_in[10];
  const float* g1_bih  = (const float*)d_in[11];
  const float* g1_bhh  = (const float*)d_in[12];
  const float* lin_W   = (const float*)d_in[13];
  const float* lin_b   = (const float*)d_in[14];
  const float* lin2_W  = (const float*)d_in[15];
  const float* lin2_b  = (const float*)d_in[16];
  const float* c_Wih   = (const float*)d_in[17];
  const float* c_Whh   = (const float*)d_in[18];
  const float* c_bih   = (const float*)d_in[19];
  const float* c_bhh   = (const float*)d_in[20];
  const float* hyp_W   = (const float*)d_in[21];
  const float* hyp_b   = (const float*)d_in[22];
  const float* bn_g    = (const float*)d_in[23];
  const float* bn_be   = (const float*)d_in[24];
  const float* bn_m    = (const float*)d_in[25];
  const float* bn_v    = (const float*)d_in[26];
  const float* out_W   = (const float*)d_in[27];
  const float* out_b   = (const float*)d_in[28];

  float* ws    = (float*)d_ws;
  float* hmsg  = ws;                       // NPAIR*128
  float* hself = ws + (size_t)NPAIR * 128; // NPAIR*128
  float* bloss = ws + (size_t)NPAIR * 256; // 256

  float* out = (float*)d_out;

  k1_msg<<<NPAIR / 16, 256, 0, stream>>>(X, C, msg_W, msg_b, lin_W, lin_b, hmsg, hself);
  k2_chain<<<N_ / 16, 256, 0, stream>>>(hmsg, hself, Y,
      g0_Wih, g0_Whh, g0_bih, g0_bhh,
      g1_Wih, g1_Whh, g1_bih, g1_bhh,
      lin2_W, lin2_b, c_Wih, c_Whh, c_bih, c_bhh,
      hyp_W, hyp_b, bn_g, bn_be, bn_m, bn_v, out_W, out_b,
      out, bloss);
  k3_loss<<<1, 256, 0, stream>>>(bloss, out);
}

// Round 2
// 1208.521 us; speedup vs baseline: 1.1498x; 1.1498x over previous
//
#include <hip/hip_runtime.h>
#include <math.h>

#define N_    4096
#define W_    7
#define NPAIR (N_ * W_)   // 28672

typedef unsigned short u16;

__device__ __forceinline__ float sigm(float x) { return 1.0f / (1.0f + __expf(-x)); }
__device__ __forceinline__ float tanh_fast(float x) { return 2.0f / (1.0f + __expf(-2.0f * x)) - 1.0f; }
__device__ __forceinline__ float bf2f(u16 u) { return __uint_as_float(((unsigned)u) << 16); }
__device__ __forceinline__ u16 f2bf(float f) {
  unsigned u = __float_as_uint(f);
  return (u16)((u + 0x7FFFu + ((u >> 16) & 1u)) >> 16);
}

// ---------------- k_conv: fp32 (strided rows of 128) -> bf16 ----------------
__global__ __launch_bounds__(256) void k_conv(const float* __restrict__ src,
                                              u16* __restrict__ dst,
                                              int total, int sstride)
{
  const int i = blockIdx.x * 256 + threadIdx.x;
  if (i < total) dst[i] = f2bf(src[(size_t)(i >> 7) * sstride + (i & 127)]);
}

// ---------------- K1: weighted neighbor reduction + msg/lin matvecs ----------------
__global__ __launch_bounds__(256) void k1_msg(
    const float* __restrict__ X, const float* __restrict__ C,
    const float* __restrict__ msg_W, const float* __restrict__ msg_b,
    const float* __restrict__ lin_W, const float* __restrict__ lin_b,
    u16* __restrict__ hmsg, u16* __restrict__ hself)
{
  __shared__ float s_xw[16][260];
  __shared__ float s_tx[16][260];
  __shared__ float s_ps[16];
  const int tid = threadIdx.x;
  const int wave = tid >> 6, lane = tid & 63;
  const int p0 = blockIdx.x * 16;

  for (int q = 0; q < 4; ++q) {
    const int lp = wave * 4 + q;
    const int p = p0 + lp;
    const int n = p / 7, w = p - n * 7;
    const float* xb = X + ((size_t)(n * 33 + 1) * 7 + w) * 256 + lane * 4;
    const float* cb = C + (size_t)(n * 33 + 1) * 7 + w;
    float4 acc = make_float4(0.f, 0.f, 0.f, 0.f);
    float ps = 0.f;
    #pragma unroll 4
    for (int m = 0; m < 32; ++m) {
      const float c = cb[m * 7];
      const float4 x4 = *(const float4*)(xb + (size_t)m * 1792);
      acc.x += c * x4.x; acc.y += c * x4.y; acc.z += c * x4.z; acc.w += c * x4.w;
      ps += c;
    }
    *(float4*)&s_xw[lp][lane * 4] = acc;
    const float4 t4 = *(const float4*)(X + ((size_t)(n * 33) * 7 + w) * 256 + lane * 4);
    *(float4*)&s_tx[lp][lane * 4] = t4;
    if (lane == 0) s_ps[lp] = ps;
  }
  __syncthreads();

  const int r = tid & 127, nh = tid >> 7;
  float accm[8], accs[8];
  const float mb = msg_b[r], lb = lin_b[r];
  #pragma unroll
  for (int j = 0; j < 8; ++j) { accm[j] = mb * s_ps[nh * 8 + j]; accs[j] = lb; }
  const float4* wm4 = (const float4*)(msg_W + (size_t)r * 256);
  const float4* wl4 = (const float4*)(lin_W + (size_t)r * 256);
  for (int k4 = 0; k4 < 64; ++k4) {
    const float4 wm = wm4[k4];
    const float4 wl = wl4[k4];
    #pragma unroll
    for (int j = 0; j < 8; ++j) {
      const float4 xa = *(const float4*)&s_xw[nh * 8 + j][k4 * 4];
      const float4 ta = *(const float4*)&s_tx[nh * 8 + j][k4 * 4];
      accm[j] += wm.x * xa.x + wm.y * xa.y + wm.z * xa.z + wm.w * xa.w;
      accs[j] += wl.x * ta.x + wl.y * ta.y + wl.z * ta.z + wl.w * ta.w;
    }
  }
  #pragma unroll
  for (int j = 0; j < 8; ++j) {
    const int p = p0 + nh * 8 + j;
    hmsg[(size_t)p * 128 + r] = f2bf(accm[j]);
    hself[(size_t)p * 128 + r] = f2bf(accs[j]);
  }
}

// ---------------- k_lin: out[P][NCOL] = in[P][128] @ W^T + bias (batched) ----------
// block = NCOL threads, 16 pairs per block. in bf16, W fp32 (row stride), out bf16.
template <int NCOL>
__global__ __launch_bounds__(NCOL) void k_lin(
    const u16* __restrict__ in, const float* __restrict__ W,
    const float* __restrict__ bias, u16* __restrict__ out, int wstride)
{
  __shared__ float s_in[128][20];
  const int tid = threadIdx.x;
  const int p0 = blockIdx.x * 16;
  for (int i = tid; i < 256; i += NCOL) {
    const int r = i >> 4, k0 = (i & 15) * 8;
    uint4 raw = *(const uint4*)&in[(size_t)(p0 + r) * 128 + k0];
    const u16* u = (const u16*)&raw;
    #pragma unroll
    for (int j = 0; j < 8; ++j) s_in[k0 + j][r] = bf2f(u[j]);
  }
  __syncthreads();
  float acc[16];
  const float b = bias[tid];
  #pragma unroll
  for (int j = 0; j < 16; ++j) acc[j] = b;
  const float4* w4 = (const float4*)(W + (size_t)tid * wstride);
  for (int k4 = 0; k4 < 32; ++k4) {
    const float4 wv = w4[k4];
    #pragma unroll
    for (int kk = 0; kk < 4; ++kk) {
      const int k = k4 * 4 + kk;
      float rv[16];
      *(float4*)&rv[0]  = *(const float4*)&s_in[k][0];
      *(float4*)&rv[4]  = *(const float4*)&s_in[k][4];
      *(float4*)&rv[8]  = *(const float4*)&s_in[k][8];
      *(float4*)&rv[12] = *(const float4*)&s_in[k][12];
      const float wk = ((const float*)&wv)[kk];
      #pragma unroll
      for (int j = 0; j < 16; ++j) acc[j] += wk * rv[j];
    }
  }
  #pragma unroll
  for (int j = 0; j < 16; ++j)
    out[(size_t)(p0 + j) * NCOL + tid] = f2bf(acc[j]);
}

// ---------------- k_rec_gru: h_t = GRU(xg_t, h_{t-1}) for 7 steps, 8 n / block -----
__global__ __launch_bounds__(256) void k_rec_gru(
    const u16* __restrict__ xg,   // [P][384] bf16 (includes bih)
    const u16* __restrict__ whh,  // [384][128] bf16
    const float* __restrict__ bhh,
    u16* __restrict__ hout)       // [P][128] bf16
{
  __shared__ float s_h[128][12];
  const int tid = threadIdx.x;
  const int d = tid & 127, nh = tid >> 7;
  const int n0 = blockIdx.x * 8;
  for (int i = tid; i < 128 * 12; i += 256) ((float*)s_h)[i] = 0.f;
  const float bR = bhh[d], bZ = bhh[d + 128], bN = bhh[d + 256];
  const u16* wR = whh + (size_t)d * 128;
  const u16* wZ = whh + (size_t)(d + 128) * 128;
  const u16* wN = whh + (size_t)(d + 256) * 128;
  __syncthreads();

  for (int w = 0; w < 7; ++w) {
    float xr[4], xz[4], xn[4], hr[4], hz[4], hn[4];
    #pragma unroll
    for (int j = 0; j < 4; ++j) {
      const size_t base = ((size_t)(n0 + nh * 4 + j) * 7 + w) * 384 + d;
      xr[j] = bf2f(xg[base]);
      xz[j] = bf2f(xg[base + 128]);
      xn[j] = bf2f(xg[base + 256]);
      hr[j] = bR; hz[j] = bZ; hn[j] = bN;
    }
    if (w) {
      for (int k4 = 0; k4 < 32; ++k4) {
        const ushort4 uR = *(const ushort4*)(wR + k4 * 4);
        const ushort4 uZ = *(const ushort4*)(wZ + k4 * 4);
        const ushort4 uN = *(const ushort4*)(wN + k4 * 4);
        #pragma unroll
        for (int kk = 0; kk < 4; ++kk) {
          float hv[4];
          *(float4*)hv = *(const float4*)&s_h[k4 * 4 + kk][nh * 4];
          const float wr_ = bf2f(((const u16*)&uR)[kk]);
          const float wz_ = bf2f(((const u16*)&uZ)[kk]);
          const float wn_ = bf2f(((const u16*)&uN)[kk]);
          #pragma unroll
          for (int j = 0; j < 4; ++j) {
            hr[j] += wr_ * hv[j];
            hz[j] += wz_ * hv[j];
            hn[j] += wn_ * hv[j];
          }
        }
      }
    }
    float hnew[4];
    #pragma unroll
    for (int j = 0; j < 4; ++j) {
      const float r = sigm(xr[j] + hr[j]);
      const float z = sigm(xz[j] + hz[j]);
      const float nn = tanh_fast(xn[j] + r * hn[j]);
      const float hold = s_h[d][nh * 4 + j];
      hnew[j] = (1.f - z) * nn + z * hold;
    }
    __syncthreads();
    #pragma unroll
    for (int j = 0; j < 4; ++j) {
      s_h[d][nh * 4 + j] = hnew[j];
      hout[((size_t)(n0 + nh * 4 + j) * 7 + w) * 128 + d] = f2bf(hnew[j]);
    }
    __syncthreads();
  }
}

// ---------------- k_rec2: cell chain + head + loss partial, 8 n / block -----------
__global__ __launch_bounds__(256) void k_rec2(
    const u16* __restrict__ xgc,   // [P][384] bf16 (includes c_bih)
    const u16* __restrict__ l2b,   // [P][128] bf16 (W2b @ h1 + lin2_b)
    const u16* __restrict__ w2a,   // [128][128] bf16 (lin2_W[:, :128])
    const u16* __restrict__ whh,   // c_Whh bf16
    const float* __restrict__ bhh,
    const float* __restrict__ hyp_W, const float* __restrict__ hyp_b,
    const float* __restrict__ bn_g, const float* __restrict__ bn_be,
    const float* __restrict__ bn_m, const float* __restrict__ bn_v,
    const float* __restrict__ out_W, const float* __restrict__ out_b,
    const float* __restrict__ Y,
    float* __restrict__ outp, float* __restrict__ bloss)
{
  __shared__ float s_hx[128][12];
  __shared__ float s_t[128][12];
  __shared__ float s_ls[8];
  const int tid = threadIdx.x;
  const int d = tid & 127, nh = tid >> 7;
  const int n0 = blockIdx.x * 8;
  for (int i = tid; i < 128 * 12; i += 256) ((float*)s_hx)[i] = 0.f;
  const float bR = bhh[d], bZ = bhh[d + 128], bN = bhh[d + 256];
  const u16* wa = w2a + (size_t)d * 128;
  const u16* wR = whh + (size_t)d * 128;
  const u16* wZ = whh + (size_t)(d + 128) * 128;
  const u16* wN = whh + (size_t)(d + 256) * 128;
  __syncthreads();

  for (int w = 0; w < 7; ++w) {
    float a2[4];
    #pragma unroll
    for (int j = 0; j < 4; ++j)
      a2[j] = bf2f(l2b[((size_t)(n0 + nh * 4 + j) * 7 + w) * 128 + d]);
    if (w) {
      for (int k4 = 0; k4 < 32; ++k4) {
        const ushort4 ua = *(const ushort4*)(wa + k4 * 4);
        #pragma unroll
        for (int kk = 0; kk < 4; ++kk) {
          float hv[4];
          *(float4*)hv = *(const float4*)&s_hx[k4 * 4 + kk][nh * 4];
          const float wv = bf2f(((const u16*)&ua)[kk]);
          #pragma unroll
          for (int j = 0; j < 4; ++j) a2[j] += wv * hv[j];
        }
      }
    }
    float hx1[4];
    #pragma unroll
    for (int j = 0; j < 4; ++j) hx1[j] = tanh_fast(a2[j]);
    __syncthreads();   // all s_hx reads (a2 matvec) + prior s_t reads done
    #pragma unroll
    for (int j = 0; j < 4; ++j) s_t[d][nh * 4 + j] = hx1[j];
    __syncthreads();   // s_t ready

    float xr[4], xz[4], xn[4], hr[4], hz[4], hn[4];
    #pragma unroll
    for (int j = 0; j < 4; ++j) {
      const size_t base = ((size_t)(n0 + nh * 4 + j) * 7 + w) * 384 + d;
      xr[j] = bf2f(xgc[base]);
      xz[j] = bf2f(xgc[base + 128]);
      xn[j] = bf2f(xgc[base + 256]);
      hr[j] = bR; hz[j] = bZ; hn[j] = bN;
    }
    for (int k4 = 0; k4 < 32; ++k4) {
      const ushort4 uR = *(const ushort4*)(wR + k4 * 4);
      const ushort4 uZ = *(const ushort4*)(wZ + k4 * 4);
      const ushort4 uN = *(const ushort4*)(wN + k4 * 4);
      #pragma unroll
      for (int kk = 0; kk < 4; ++kk) {
        float hv[4];
        *(float4*)hv = *(const float4*)&s_t[k4 * 4 + kk][nh * 4];
        const float wr_ = bf2f(((const u16*)&uR)[kk]);
        const float wz_ = bf2f(((const u16*)&uZ)[kk]);
        const float wn_ = bf2f(((const u16*)&uN)[kk]);
        #pragma unroll
        for (int j = 0; j < 4; ++j) {
          hr[j] += wr_ * hv[j];
          hz[j] += wz_ * hv[j];
          hn[j] += wn_ * hv[j];
        }
      }
    }
    #pragma unroll
    for (int j = 0; j < 4; ++j) {
      const float r = sigm(xr[j] + hr[j]);
      const float z = sigm(xz[j] + hz[j]);
      const float nn = tanh_fast(xn[j] + r * hn[j]);
      s_hx[d][nh * 4 + j] = (1.f - z) * nn + z * hx1[j];
    }
    __syncthreads();   // s_hx ready for next step / head
  }

  // head: relu(BN(hyp_W @ hx + hyp_b)) -> y -> sigmoid + loss
  float ah[4];
  {
    const float bh = hyp_b[d];
    #pragma unroll
    for (int j = 0; j < 4; ++j) ah[j] = bh;
    const float4* wh4 = (const float4*)(hyp_W + (size_t)d * 128);
    for (int k4 = 0; k4 < 32; ++k4) {
      const float4 wv = wh4[k4];
      #pragma unroll
      for (int kk = 0; kk < 4; ++kk) {
        float hv[4];
        *(float4*)hv = *(const float4*)&s_hx[k4 * 4 + kk][nh * 4];
        const float wk = ((const float*)&wv)[kk];
        #pragma unroll
        for (int j = 0; j < 4; ++j) ah[j] += wk * hv[j];
      }
    }
  }
  const float sc = rsqrtf(bn_v[d] + 1e-5f) * bn_g[d];
  const float mu = bn_m[d], be = bn_be[d];
  __syncthreads();
  #pragma unroll
  for (int j = 0; j < 4; ++j)
    s_t[d][nh * 4 + j] = fmaxf((ah[j] - mu) * sc + be, 0.f);
  __syncthreads();
  if (tid < 8) {
    const int n = tid;
    float y = out_b[0];
    for (int jj = 0; jj < 128; ++jj) y += out_W[jj] * s_t[jj][n];
    outp[1 + n0 + n] = 1.f / (1.f + __expf(-y));
    const float tY = Y[(size_t)(n0 + n) * 33];
    s_ls[n] = fmaxf(y, 0.f) - y * tY + log1pf(__expf(-fabsf(y)));
  }
  __syncthreads();
  if (tid == 0) {
    float s = 0.f;
    #pragma unroll
    for (int j = 0; j < 8; ++j) s += s_ls[j];
    bloss[blockIdx.x] = s;
  }
}

// ---------------- K3: loss reduction (512 partials) ----------------
__global__ __launch_bounds__(256) void k3_loss(const float* __restrict__ bloss,
                                               float* __restrict__ out)
{
  __shared__ float s[256];
  s[threadIdx.x] = bloss[threadIdx.x] + bloss[threadIdx.x + 256];
  __syncthreads();
  for (int off = 128; off > 0; off >>= 1) {
    if (threadIdx.x < off) s[threadIdx.x] += s[threadIdx.x + off];
    __syncthreads();
  }
  if (threadIdx.x == 0) out[0] = s[0] * (1.0f / 4096.0f);
}

extern "C" void kernel_launch(void* const* d_in, const int* in_sizes, int n_in,
                              void* d_out, int out_size, void* d_ws, size_t ws_size,
                              hipStream_t stream) {
  const float* X       = (const float*)d_in[0];
  const float* Y       = (const float*)d_in[1];
  const float* C       = (const float*)d_in[2];
  const float* msg_W   = (const float*)d_in[3];
  const float* msg_b   = (const float*)d_in[4];
  const float* g0_Wih  = (const float*)d_in[5];
  const float* g0_Whh  = (const float*)d_in[6];
  const float* g0_bih  = (const float*)d_in[7];
  const float* g0_bhh  = (const float*)d_in[8];
  const float* g1_Wih  = (const float*)d_in[9];
  const float* g1_Whh  = (const float*)d_in[10];
  const float* g1_bih  = (const float*)d_in[11];
  const float* g1_bhh  = (const float*)d_in[12];
  const float* lin_W   = (const float*)d_in[13];
  const float* lin_b   = (const float*)d_in[14];
  const float* lin2_W  = (const float*)d_in[15];
  const float* lin2_b  = (const float*)d_in[16];
  const float* c_Wih   = (const float*)d_in[17];
  const float* c_Whh   = (const float*)d_in[18];
  const float* c_bih   = (const float*)d_in[19];
  const float* c_bhh   = (const float*)d_in[20];
  const float* hyp_W   = (const float*)d_in[21];
  const float* hyp_b   = (const float*)d_in[22];
  const float* bn_g    = (const float*)d_in[23];
  const float* bn_be   = (const float*)d_in[24];
  const float* bn_m    = (const float*)d_in[25];
  const float* bn_v    = (const float*)d_in[26];
  const float* out_W   = (const float*)d_in[27];
  const float* out_b   = (const float*)d_in[28];

  u16* hmsg  = (u16*)d_ws;
  u16* hself = hmsg  + (size_t)NPAIR * 128;
  u16* xgbuf = hself + (size_t)NPAIR * 128;
  u16* h0buf = xgbuf + (size_t)NPAIR * 384;
  u16* h1buf = h0buf + (size_t)NPAIR * 128;
  u16* l2buf = h1buf + (size_t)NPAIR * 128;
  u16* whh0  = l2buf + (size_t)NPAIR * 128;
  u16* whh1  = whh0 + 49152;
  u16* whhc  = whh1 + 49152;
  u16* w2a   = whhc + 49152;
  float* bloss = (float*)(w2a + 16384);

  float* out = (float*)d_out;

  // weight conversions (independent of data path)
  k_conv<<<192, 256, 0, stream>>>(g0_Whh, whh0, 49152, 128);
  k_conv<<<192, 256, 0, stream>>>(g1_Whh, whh1, 49152, 128);
  k_conv<<<192, 256, 0, stream>>>(c_Whh,  whhc, 49152, 128);
  k_conv<<<64, 256, 0, stream>>>(lin2_W, w2a, 16384, 256);

  k1_msg<<<NPAIR / 16, 256, 0, stream>>>(X, C, msg_W, msg_b, lin_W, lin_b, hmsg, hself);

  k_lin<384><<<NPAIR / 16, 384, 0, stream>>>(hmsg, g0_Wih, g0_bih, xgbuf, 128);
  k_rec_gru<<<N_ / 8, 256, 0, stream>>>(xgbuf, whh0, g0_bhh, h0buf);
  k_lin<384><<<NPAIR / 16, 384, 0, stream>>>(h0buf, g1_Wih, g1_bih, xgbuf, 128);
  k_rec_gru<<<N_ / 8, 256, 0, stream>>>(xgbuf, whh1, g1_bhh, h1buf);
  k_lin<128><<<NPAIR / 16, 128, 0, stream>>>(h1buf, lin2_W + 128, lin2_b, l2buf, 256);
  k_lin<384><<<NPAIR / 16, 384, 0, stream>>>(hself, c_Wih, c_bih, xgbuf, 128);

  k_rec2<<<N_ / 8, 256, 0, stream>>>(xgbuf, l2buf, w2a, whhc, c_bhh,
      hyp_W, hyp_b, bn_g, bn_be, bn_m, bn_v, out_W, out_b, Y, out, bloss);
  k3_loss<<<1, 256, 0, stream>>>(bloss, out);
}

// Round 3
// 934.978 us; speedup vs baseline: 1.4862x; 1.2926x over previous
//
#include <hip/hip_runtime.h>
#include <math.h>

#define N_    4096
#define W_    7
#define NPAIR (N_ * W_)   // 28672

typedef unsigned short u16;
typedef __attribute__((ext_vector_type(8))) short bf16x8;
typedef __attribute__((ext_vector_type(4))) float f32x4;

__device__ __forceinline__ float sigm(float x) { return 1.0f / (1.0f + __expf(-x)); }
__device__ __forceinline__ float tanh_fast(float x) { return 2.0f / (1.0f + __expf(-2.0f * x)) - 1.0f; }
__device__ __forceinline__ float bf2f(u16 u) { return __uint_as_float(((unsigned)u) << 16); }
__device__ __forceinline__ u16 f2bf(float f) {
  unsigned u = __float_as_uint(f);
  return (u16)((u + 0x7FFFu + ((u >> 16) & 1u)) >> 16);
}

// ---------------- k_prep: fp32 weight [R][KS] (+bias) -> bf16 [R][KD] ----------------
__global__ __launch_bounds__(256) void k_prep(
    const float* __restrict__ W, int wstride, int koff,
    const float* __restrict__ bias, u16* __restrict__ dst,
    int R, int KS, int KD)
{
  const int i = blockIdx.x * 256 + threadIdx.x;
  if (i >= R * KD) return;
  const int r = i / KD, k = i - r * KD;
  float v = 0.f;
  if (k < KS) v = W[(size_t)r * wstride + koff + k];
  else if (k == KS && bias) v = bias[r];
  dst[i] = f2bf(v);
}

// ---------------- k_slots: set bias slot (1.0 + zeros) at elems [128..160) ----------
__global__ __launch_bounds__(256) void k_slots(u16* __restrict__ b0, u16* __restrict__ b1,
                                               u16* __restrict__ b2, u16* __restrict__ b3)
{
  const int i = blockIdx.x * 256 + threadIdx.x;   // i in [0, 4*NPAIR)
  const int which = i / NPAIR, r = i - which * NPAIR;
  u16* base = (which == 0) ? b0 : (which == 1) ? b1 : (which == 2) ? b2 : b3;
  u16* p = base + (size_t)r * 160 + 128;
  ushort4 z1 = {0x3F80u, 0, 0, 0}, z = {0, 0, 0, 0};
  *(ushort4*)(p) = z1;
  #pragma unroll
  for (int j = 1; j < 8; ++j) *(ushort4*)(p + j * 4) = z;
}

// ---------------- k1p1: stream X -> xw (weighted neighbor sum), tx (target) --------
// rows are [P][288] bf16: [0..255]=data, 256 = ps (or 1.0), 257..287 = 0
__global__ __launch_bounds__(256) void k1p1(
    const float* __restrict__ X, const float* __restrict__ C,
    u16* __restrict__ xw, u16* __restrict__ tx)
{
  const int tid = threadIdx.x, wave = tid >> 6, lane = tid & 63;
  const int p0 = blockIdx.x * 16;
  for (int q = 0; q < 4; ++q) {
    const int p = p0 + wave * 4 + q;
    const int n = p / 7, w = p - n * 7;
    const float* xb = X + ((size_t)(n * 33 + 1) * 7 + w) * 256 + lane * 4;
    const float* cb = C + (size_t)(n * 33 + 1) * 7 + w;
    float4 acc = make_float4(0.f, 0.f, 0.f, 0.f);
    float ps = 0.f;
    #pragma unroll 4
    for (int m = 0; m < 32; ++m) {
      const float c = cb[m * 7];
      const float4 x4 = *(const float4*)(xb + (size_t)m * 1792);
      acc.x += c * x4.x; acc.y += c * x4.y; acc.z += c * x4.z; acc.w += c * x4.w;
      ps += c;
    }
    ushort4 o = {f2bf(acc.x), f2bf(acc.y), f2bf(acc.z), f2bf(acc.w)};
    *(ushort4*)(xw + (size_t)p * 288 + lane * 4) = o;
    const float4 t4 = *(const float4*)(X + ((size_t)(n * 33) * 7 + w) * 256 + lane * 4);
    ushort4 ot = {f2bf(t4.x), f2bf(t4.y), f2bf(t4.z), f2bf(t4.w)};
    *(ushort4*)(tx + (size_t)p * 288 + lane * 4) = ot;
    if (lane < 8) {
      ushort4 zp = {0, 0, 0, 0}, z1 = {0, 0, 0, 0};
      if (lane == 0) { zp.x = f2bf(ps); z1.x = 0x3F80u; }
      *(ushort4*)(xw + (size_t)p * 288 + 256 + lane * 4) = zp;
      *(ushort4*)(tx + (size_t)p * 288 + 256 + lane * 4) = z1;
    }
  }
}

// ---------------- k_gemm: out[P][ldout] = A[P][lda] @ BT[NCOL][ldb]^T (bf16 MFMA) ----
// KC = K/32 chunks; LDK = padded LDS row elems (LDK*2 % 128 == 0).
// Tile 64x64, 4 waves (wave = 16 rows), full-K single stage, XOR-swizzled LDS.
template <int KC, int LDK>
__global__ __launch_bounds__(256) void k_gemm(
    const u16* __restrict__ A, int lda,
    const u16* __restrict__ BT, int ldb,
    u16* __restrict__ out, int ldout)
{
  constexpr int K = KC * 32;
  constexpr int KD8 = K / 8;           // 16B chunks per row
  __shared__ u16 sA[64 * LDK];
  __shared__ u16 sB[64 * LDK];
  const int tid = threadIdx.x;
  const int p0 = blockIdx.x * 64, c0 = blockIdx.y * 64;

  // stage A and B tiles (64 rows x K) with byte-swizzle  b ^= (row&7)<<4
  #pragma unroll
  for (int it = 0; it < (64 * KD8) / 256; ++it) {
    const int c = it * 256 + tid;
    const int row = c / KD8, k8 = c - row * KD8;
    const int se = row * LDK + (((k8 * 16) ^ ((row & 7) << 4)) >> 1);
    *(uint4*)&sA[se] = *(const uint4*)(A + (size_t)(p0 + row) * lda + k8 * 8);
    *(uint4*)&sB[se] = *(const uint4*)(BT + (size_t)(c0 + row) * ldb + k8 * 8);
  }
  __syncthreads();

  const int lane = tid & 63, wave = tid >> 6;
  const int r0 = wave * 16;
  const int frow = lane & 15;          // fragment row (A) / col (B)
  const int kbase2 = ((lane >> 4) * 8) * 2;  // byte offset of this lane's k-chunk

  bf16x8 af[KC];
  #pragma unroll
  for (int kc = 0; kc < KC; ++kc) {
    const int row = r0 + frow;
    af[kc] = *(const bf16x8*)&sA[row * LDK + (((kc * 64 + kbase2) ^ ((row & 7) << 4)) >> 1)];
  }

  f32x4 acc[4];
  #pragma unroll
  for (int ct = 0; ct < 4; ++ct) acc[ct] = (f32x4){0.f, 0.f, 0.f, 0.f};

  #pragma unroll
  for (int ct = 0; ct < 4; ++ct) {
    const int brow = ct * 16 + frow;
    #pragma unroll
    for (int kc = 0; kc < KC; ++kc) {
      const bf16x8 bfr = *(const bf16x8*)&sB[brow * LDK + (((kc * 64 + kbase2) ^ ((brow & 7) << 4)) >> 1)];
      acc[ct] = __builtin_amdgcn_mfma_f32_16x16x32_bf16(af[kc], bfr, acc[ct], 0, 0, 0);
    }
  }

  // C layout (m89): col = lane&15, row = (lane>>4)*4 + reg
  const int orow = p0 + r0 + (lane >> 4) * 4;
  #pragma unroll
  for (int ct = 0; ct < 4; ++ct) {
    const int col = c0 + ct * 16 + (lane & 15);
    #pragma unroll
    for (int reg = 0; reg < 4; ++reg)
      out[(size_t)(orow + reg) * ldout + col] = f2bf(acc[ct][reg]);
  }
}

// ---------------- k_rec_gru: h_t = GRU(xg_t, h_{t-1}) for 7 steps, 8 n / block -----
__global__ __launch_bounds__(256) void k_rec_gru(
    const u16* __restrict__ xg,   // [P][384] bf16 (includes bih)
    const u16* __restrict__ whh,  // [384][128] bf16
    const float* __restrict__ bhh,
    u16* __restrict__ hout)       // [P][160] bf16 (slots pre-filled)
{
  __shared__ float s_h[128][12];
  const int tid = threadIdx.x;
  const int d = tid & 127, nh = tid >> 7;
  const int n0 = blockIdx.x * 8;
  for (int i = tid; i < 128 * 12; i += 256) ((float*)s_h)[i] = 0.f;
  const float bR = bhh[d], bZ = bhh[d + 128], bN = bhh[d + 256];
  const u16* wR = whh + (size_t)d * 128;
  const u16* wZ = whh + (size_t)(d + 128) * 128;
  const u16* wN = whh + (size_t)(d + 256) * 128;
  __syncthreads();

  for (int w = 0; w < 7; ++w) {
    float xr[4], xz[4], xn[4], hr[4], hz[4], hn[4];
    #pragma unroll
    for (int j = 0; j < 4; ++j) {
      const size_t base = ((size_t)(n0 + nh * 4 + j) * 7 + w) * 384 + d;
      xr[j] = bf2f(xg[base]);
      xz[j] = bf2f(xg[base + 128]);
      xn[j] = bf2f(xg[base + 256]);
      hr[j] = bR; hz[j] = bZ; hn[j] = bN;
    }
    if (w) {
      for (int k4 = 0; k4 < 32; ++k4) {
        const ushort4 uR = *(const ushort4*)(wR + k4 * 4);
        const ushort4 uZ = *(const ushort4*)(wZ + k4 * 4);
        const ushort4 uN = *(const ushort4*)(wN + k4 * 4);
        #pragma unroll
        for (int kk = 0; kk < 4; ++kk) {
          float hv[4];
          *(float4*)hv = *(const float4*)&s_h[k4 * 4 + kk][nh * 4];
          const float wr_ = bf2f(((const u16*)&uR)[kk]);
          const float wz_ = bf2f(((const u16*)&uZ)[kk]);
          const float wn_ = bf2f(((const u16*)&uN)[kk]);
          #pragma unroll
          for (int j = 0; j < 4; ++j) {
            hr[j] += wr_ * hv[j];
            hz[j] += wz_ * hv[j];
            hn[j] += wn_ * hv[j];
          }
        }
      }
    }
    float hnew[4];
    #pragma unroll
    for (int j = 0; j < 4; ++j) {
      const float r = sigm(xr[j] + hr[j]);
      const float z = sigm(xz[j] + hz[j]);
      const float nn = tanh_fast(xn[j] + r * hn[j]);
      const float hold = s_h[d][nh * 4 + j];
      hnew[j] = (1.f - z) * nn + z * hold;
    }
    __syncthreads();
    #pragma unroll
    for (int j = 0; j < 4; ++j) {
      s_h[d][nh * 4 + j] = hnew[j];
      hout[((size_t)(n0 + nh * 4 + j) * 7 + w) * 160 + d] = f2bf(hnew[j]);
    }
    __syncthreads();
  }
}

// ---------------- k_rec2: cell chain + head + loss partial, 8 n / block -----------
__global__ __launch_bounds__(256) void k_rec2(
    const u16* __restrict__ xgc,   // [P][384] bf16 (includes c_bih)
    const u16* __restrict__ l2b,   // [P][128] bf16 (W2b @ h1 + lin2_b)
    const u16* __restrict__ w2a,   // [128][128] bf16 (lin2_W[:, :128])
    const u16* __restrict__ whh,   // c_Whh bf16
    const float* __restrict__ bhh,
    const float* __restrict__ hyp_W, const float* __restrict__ hyp_b,
    const float* __restrict__ bn_g, const float* __restrict__ bn_be,
    const float* __restrict__ bn_m, const float* __restrict__ bn_v,
    const float* __restrict__ out_W, const float* __restrict__ out_b,
    const float* __restrict__ Y,
    float* __restrict__ outp, float* __restrict__ bloss)
{
  __shared__ float s_hx[128][12];
  __shared__ float s_t[128][12];
  __shared__ float s_ls[8];
  const int tid = threadIdx.x;
  const int d = tid & 127, nh = tid >> 7;
  const int n0 = blockIdx.x * 8;
  for (int i = tid; i < 128 * 12; i += 256) ((float*)s_hx)[i] = 0.f;
  const float bR = bhh[d], bZ = bhh[d + 128], bN = bhh[d + 256];
  const u16* wa = w2a + (size_t)d * 128;
  const u16* wR = whh + (size_t)d * 128;
  const u16* wZ = whh + (size_t)(d + 128) * 128;
  const u16* wN = whh + (size_t)(d + 256) * 128;
  __syncthreads();

  for (int w = 0; w < 7; ++w) {
    float a2[4];
    #pragma unroll
    for (int j = 0; j < 4; ++j)
      a2[j] = bf2f(l2b[((size_t)(n0 + nh * 4 + j) * 7 + w) * 128 + d]);
    if (w) {
      for (int k4 = 0; k4 < 32; ++k4) {
        const ushort4 ua = *(const ushort4*)(wa + k4 * 4);
        #pragma unroll
        for (int kk = 0; kk < 4; ++kk) {
          float hv[4];
          *(float4*)hv = *(const float4*)&s_hx[k4 * 4 + kk][nh * 4];
          const float wv = bf2f(((const u16*)&ua)[kk]);
          #pragma unroll
          for (int j = 0; j < 4; ++j) a2[j] += wv * hv[j];
        }
      }
    }
    float hx1[4];
    #pragma unroll
    for (int j = 0; j < 4; ++j) hx1[j] = tanh_fast(a2[j]);
    __syncthreads();
    #pragma unroll
    for (int j = 0; j < 4; ++j) s_t[d][nh * 4 + j] = hx1[j];
    __syncthreads();

    float xr[4], xz[4], xn[4], hr[4], hz[4], hn[4];
    #pragma unroll
    for (int j = 0; j < 4; ++j) {
      const size_t base = ((size_t)(n0 + nh * 4 + j) * 7 + w) * 384 + d;
      xr[j] = bf2f(xgc[base]);
      xz[j] = bf2f(xgc[base + 128]);
      xn[j] = bf2f(xgc[base + 256]);
      hr[j] = bR; hz[j] = bZ; hn[j] = bN;
    }
    for (int k4 = 0; k4 < 32; ++k4) {
      const ushort4 uR = *(const ushort4*)(wR + k4 * 4);
      const ushort4 uZ = *(const ushort4*)(wZ + k4 * 4);
      const ushort4 uN = *(const ushort4*)(wN + k4 * 4);
      #pragma unroll
      for (int kk = 0; kk < 4; ++kk) {
        float hv[4];
        *(float4*)hv = *(const float4*)&s_t[k4 * 4 + kk][nh * 4];
        const float wr_ = bf2f(((const u16*)&uR)[kk]);
        const float wz_ = bf2f(((const u16*)&uZ)[kk]);
        const float wn_ = bf2f(((const u16*)&uN)[kk]);
        #pragma unroll
        for (int j = 0; j < 4; ++j) {
          hr[j] += wr_ * hv[j];
          hz[j] += wz_ * hv[j];
          hn[j] += wn_ * hv[j];
        }
      }
    }
    #pragma unroll
    for (int j = 0; j < 4; ++j) {
      const float r = sigm(xr[j] + hr[j]);
      const float z = sigm(xz[j] + hz[j]);
      const float nn = tanh_fast(xn[j] + r * hn[j]);
      s_hx[d][nh * 4 + j] = (1.f - z) * nn + z * hx1[j];
    }
    __syncthreads();
  }

  // head
  float ah[4];
  {
    const float bh = hyp_b[d];
    #pragma unroll
    for (int j = 0; j < 4; ++j) ah[j] = bh;
    const float4* wh4 = (const float4*)(hyp_W + (size_t)d * 128);
    for (int k4 = 0; k4 < 32; ++k4) {
      const float4 wv = wh4[k4];
      #pragma unroll
      for (int kk = 0; kk < 4; ++kk) {
        float hv[4];
        *(float4*)hv = *(const float4*)&s_hx[k4 * 4 + kk][nh * 4];
        const float wk = ((const float*)&wv)[kk];
        #pragma unroll
        for (int j = 0; j < 4; ++j) ah[j] += wk * hv[j];
      }
    }
  }
  const float sc = rsqrtf(bn_v[d] + 1e-5f) * bn_g[d];
  const float mu = bn_m[d], be = bn_be[d];
  __syncthreads();
  #pragma unroll
  for (int j = 0; j < 4; ++j)
    s_t[d][nh * 4 + j] = fmaxf((ah[j] - mu) * sc + be, 0.f);
  __syncthreads();
  if (tid < 8) {
    const int n = tid;
    float y = out_b[0];
    for (int jj = 0; jj < 128; ++jj) y += out_W[jj] * s_t[jj][n];
    outp[1 + n0 + n] = 1.f / (1.f + __expf(-y));
    const float tY = Y[(size_t)(n0 + n) * 33];
    s_ls[n] = fmaxf(y, 0.f) - y * tY + log1pf(__expf(-fabsf(y)));
  }
  __syncthreads();
  if (tid == 0) {
    float s = 0.f;
    #pragma unroll
    for (int j = 0; j < 8; ++j) s += s_ls[j];
    bloss[blockIdx.x] = s;
  }
}

// ---------------- K3: loss reduction (512 partials) ----------------
__global__ __launch_bounds__(256) void k3_loss(const float* __restrict__ bloss,
                                               float* __restrict__ out)
{
  __shared__ float s[256];
  s[threadIdx.x] = bloss[threadIdx.x] + bloss[threadIdx.x + 256];
  __syncthreads();
  for (int off = 128; off > 0; off >>= 1) {
    if (threadIdx.x < off) s[threadIdx.x] += s[threadIdx.x + off];
    __syncthreads();
  }
  if (threadIdx.x == 0) out[0] = s[0] * (1.0f / 4096.0f);
}

extern "C" void kernel_launch(void* const* d_in, const int* in_sizes, int n_in,
                              void* d_out, int out_size, void* d_ws, size_t ws_size,
                              hipStream_t stream) {
  const float* X       = (const float*)d_in[0];
  const float* Y       = (const float*)d_in[1];
  const float* C       = (const float*)d_in[2];
  const float* msg_W   = (const float*)d_in[3];
  const float* msg_b   = (const float*)d_in[4];
  const float* g0_Wih  = (const float*)d_in[5];
  const float* g0_Whh  = (const float*)d_in[6];
  const float* g0_bih  = (const float*)d_in[7];
  const float* g0_bhh  = (const float*)d_in[8];
  const float* g1_Wih  = (const float*)d_in[9];
  const float* g1_Whh  = (const float*)d_in[10];
  const float* g1_bih  = (const float*)d_in[11];
  const float* g1_bhh  = (const float*)d_in[12];
  const float* lin_W   = (const float*)d_in[13];
  const float* lin_b   = (const float*)d_in[14];
  const float* lin2_W  = (const float*)d_in[15];
  const float* lin2_b  = (const float*)d_in[16];
  const float* c_Wih   = (const float*)d_in[17];
  const float* c_Whh   = (const float*)d_in[18];
  const float* c_bih   = (const float*)d_in[19];
  const float* c_bhh   = (const float*)d_in[20];
  const float* hyp_W   = (const float*)d_in[21];
  const float* hyp_b   = (const float*)d_in[22];
  const float* bn_g    = (const float*)d_in[23];
  const float* bn_be   = (const float*)d_in[24];
  const float* bn_m    = (const float*)d_in[25];
  const float* bn_v    = (const float*)d_in[26];
  const float* out_W   = (const float*)d_in[27];
  const float* out_b   = (const float*)d_in[28];

  u16* xw    = (u16*)d_ws;                         // [P][288]
  u16* tx    = xw    + (size_t)NPAIR * 288;        // [P][288]
  u16* hmsg  = tx    + (size_t)NPAIR * 288;        // [P][160]
  u16* hself = hmsg  + (size_t)NPAIR * 160;        // [P][160]
  u16* h0b   = hself + (size_t)NPAIR * 160;        // [P][160]
  u16* h1b   = h0b   + (size_t)NPAIR * 160;        // [P][160]
  u16* xg    = h1b   + (size_t)NPAIR * 160;        // [P][384]
  u16* l2    = xg    + (size_t)NPAIR * 384;        // [P][128]
  u16* bt_msg = l2 + (size_t)NPAIR * 128;          // [128][288]
  u16* bt_lin = bt_msg + 128 * 288;                // [128][288]
  u16* bt_g0  = bt_lin + 128 * 288;                // [384][160]
  u16* bt_g1  = bt_g0 + 384 * 160;
  u16* bt_c   = bt_g1 + 384 * 160;
  u16* bt_l2  = bt_c + 384 * 160;                  // [128][160]
  u16* whh0   = bt_l2 + 128 * 160;                 // [384][128]
  u16* whh1   = whh0 + 384 * 128;
  u16* whhc   = whh1 + 384 * 128;
  u16* w2a    = whhc + 384 * 128;                  // [128][128]
  float* bloss = (float*)(w2a + 128 * 128);

  float* out = (float*)d_out;

  // weight prep (independent, tiny)
  k_prep<<<144, 256, 0, stream>>>(msg_W, 256, 0, msg_b, bt_msg, 128, 256, 288);
  k_prep<<<144, 256, 0, stream>>>(lin_W, 256, 0, lin_b, bt_lin, 128, 256, 288);
  k_prep<<<240, 256, 0, stream>>>(g0_Wih, 128, 0, g0_bih, bt_g0, 384, 128, 160);
  k_prep<<<240, 256, 0, stream>>>(g1_Wih, 128, 0, g1_bih, bt_g1, 384, 128, 160);
  k_prep<<<240, 256, 0, stream>>>(c_Wih, 128, 0, c_bih, bt_c, 384, 128, 160);
  k_prep<<<80, 256, 0, stream>>>(lin2_W, 256, 128, lin2_b, bt_l2, 128, 128, 160);
  k_prep<<<192, 256, 0, stream>>>(g0_Whh, 128, 0, nullptr, whh0, 384, 128, 128);
  k_prep<<<192, 256, 0, stream>>>(g1_Whh, 128, 0, nullptr, whh1, 384, 128, 128);
  k_prep<<<192, 256, 0, stream>>>(c_Whh, 128, 0, nullptr, whhc, 384, 128, 128);
  k_prep<<<64, 256, 0, stream>>>(lin2_W, 256, 0, nullptr, w2a, 128, 128, 128);
  k_slots<<<4 * NPAIR / 256, 256, 0, stream>>>(hmsg, hself, h0b, h1b);

  // HBM streamer
  k1p1<<<NPAIR / 16, 256, 0, stream>>>(X, C, xw, tx);

  // GEMMs (MFMA) + recurrences
  k_gemm<9, 320><<<dim3(448, 2), 256, 0, stream>>>(xw, 288, bt_msg, 288, hmsg, 160);
  k_gemm<9, 320><<<dim3(448, 2), 256, 0, stream>>>(tx, 288, bt_lin, 288, hself, 160);
  k_gemm<5, 192><<<dim3(448, 6), 256, 0, stream>>>(hmsg, 160, bt_g0, 160, xg, 384);
  k_rec_gru<<<N_ / 8, 256, 0, stream>>>(xg, whh0, g0_bhh, h0b);
  k_gemm<5, 192><<<dim3(448, 6), 256, 0, stream>>>(h0b, 160, bt_g1, 160, xg, 384);
  k_rec_gru<<<N_ / 8, 256, 0, stream>>>(xg, whh1, g1_bhh, h1b);
  k_gemm<5, 192><<<dim3(448, 2), 256, 0, stream>>>(h1b, 160, bt_l2, 160, l2, 128);
  k_gemm<5, 192><<<dim3(448, 6), 256, 0, stream>>>(hself, 160, bt_c, 160, xg, 384);

  k_rec2<<<N_ / 8, 256, 0, stream>>>(xg, l2, w2a, whhc, c_bhh,
      hyp_W, hyp_b, bn_g, bn_be, bn_m, bn_v, out_W, out_b, Y, out, bloss);
  k3_loss<<<1, 256, 0, stream>>>(bloss, out);
}

// Round 4
// 356.414 us; speedup vs baseline: 3.8989x; 2.6233x over previous
//
#include <hip/hip_runtime.h>
#include <math.h>

#define N_    4096
#define W_    7
#define NPAIR (N_ * W_)   // 28672

typedef unsigned short u16;
typedef __attribute__((ext_vector_type(8))) short bf16x8;
typedef __attribute__((ext_vector_type(4))) float f32x4;

__device__ __forceinline__ float sigm(float x) { return 1.0f / (1.0f + __expf(-x)); }
__device__ __forceinline__ float tanh_fast(float x) { return 2.0f / (1.0f + __expf(-2.0f * x)) - 1.0f; }
__device__ __forceinline__ float bf2f(u16 u) { return __uint_as_float(((unsigned)u) << 16); }
__device__ __forceinline__ u16 f2bf(float f) {
  unsigned u = __float_as_uint(f);
  return (u16)((u + 0x7FFFu + ((u >> 16) & 1u)) >> 16);
}

// ---------------- k_prep_all: all weight conversions in ONE launch -----------------
// task = blockIdx.y. Dst regions are contiguous in wbase (offsets below).
__global__ __launch_bounds__(256) void k_prep_all(
    const float* __restrict__ msg_W, const float* __restrict__ msg_b,
    const float* __restrict__ lin_W, const float* __restrict__ lin_b,
    const float* __restrict__ g0_Wih, const float* __restrict__ g1_Wih,
    const float* __restrict__ c_Wih, const float* __restrict__ lin2_W,
    const float* __restrict__ g0_Whh, const float* __restrict__ g1_Whh,
    const float* __restrict__ c_Whh, const float* __restrict__ hyp_W,
    u16* __restrict__ wbase)
{
  const int task = blockIdx.y;
  const int i = blockIdx.x * 256 + threadIdx.x;
  int R, KD, KS, stride, koff, doff;
  const float *src; const float *bias = nullptr;
  switch (task) {
    case 0:  R=128; KD=288; KS=256; stride=256; koff=0;   src=msg_W;  bias=msg_b; doff=0;      break;
    case 1:  R=128; KD=288; KS=256; stride=256; koff=0;   src=lin_W;  bias=lin_b; doff=36864;  break;
    case 2:  R=384; KD=128; KS=128; stride=128; koff=0;   src=g0_Wih;             doff=73728;  break;
    case 3:  R=384; KD=128; KS=128; stride=128; koff=0;   src=g1_Wih;             doff=122880; break;
    case 4:  R=384; KD=128; KS=128; stride=128; koff=0;   src=c_Wih;              doff=172032; break;
    case 5:  R=128; KD=128; KS=128; stride=256; koff=128; src=lin2_W;             doff=221184; break;
    case 6:  R=128; KD=128; KS=128; stride=256; koff=0;   src=lin2_W;             doff=237568; break;
    case 7:  R=384; KD=128; KS=128; stride=128; koff=0;   src=g0_Whh;             doff=253952; break;
    case 8:  R=384; KD=128; KS=128; stride=128; koff=0;   src=g1_Whh;             doff=303104; break;
    case 9:  R=384; KD=128; KS=128; stride=128; koff=0;   src=c_Whh;              doff=352256; break;
    default: R=128; KD=128; KS=128; stride=128; koff=0;   src=hyp_W;              doff=401408; break;
  }
  if (i >= R * KD) return;
  const int r = i / KD, k = i - r * KD;
  float v = 0.f;
  if (k < KS) v = src[(size_t)r * stride + koff + k];
  else if (k == KS && bias) v = bias[r];
  wbase[doff + i] = f2bf(v);
}

// ---------------- k1p1: stream X -> xw (weighted neighbor sum), tx (target) --------
// rows [P][288] bf16: [0..255]=data, 256 = ps (or 1.0), 257..287 = 0
__global__ __launch_bounds__(256) void k1p1(
    const float* __restrict__ X, const float* __restrict__ C,
    u16* __restrict__ xw, u16* __restrict__ tx)
{
  const int tid = threadIdx.x, wave = tid >> 6, lane = tid & 63;
  const int p0 = blockIdx.x * 16;
  for (int q = 0; q < 4; ++q) {
    const int p = p0 + wave * 4 + q;
    const int n = p / 7, w = p - n * 7;
    const float* xb = X + ((size_t)(n * 33 + 1) * 7 + w) * 256 + lane * 4;
    const float* cb = C + (size_t)(n * 33 + 1) * 7 + w;
    float4 acc = make_float4(0.f, 0.f, 0.f, 0.f);
    float ps = 0.f;
    #pragma unroll 4
    for (int m = 0; m < 32; ++m) {
      const float c = cb[m * 7];
      const float4 x4 = *(const float4*)(xb + (size_t)m * 1792);
      acc.x += c * x4.x; acc.y += c * x4.y; acc.z += c * x4.z; acc.w += c * x4.w;
      ps += c;
    }
    ushort4 o = {f2bf(acc.x), f2bf(acc.y), f2bf(acc.z), f2bf(acc.w)};
    *(ushort4*)(xw + (size_t)p * 288 + lane * 4) = o;
    const float4 t4 = *(const float4*)(X + ((size_t)(n * 33) * 7 + w) * 256 + lane * 4);
    ushort4 ot = {f2bf(t4.x), f2bf(t4.y), f2bf(t4.z), f2bf(t4.w)};
    *(ushort4*)(tx + (size_t)p * 288 + lane * 4) = ot;
    if (lane < 8) {
      ushort4 zp = {0, 0, 0, 0}, z1 = {0, 0, 0, 0};
      if (lane == 0) { zp.x = f2bf(ps); z1.x = 0x3F80u; }
      *(ushort4*)(xw + (size_t)p * 288 + 256 + lane * 4) = zp;
      *(ushort4*)(tx + (size_t)p * 288 + 256 + lane * 4) = z1;
    }
  }
}

// ---------------- k_gemm2: dual GEMM (set picked by blockIdx.y), 64x64 MFMA tiles ---
template <int KC, int LDK>
__global__ __launch_bounds__(256) void k_gemm2(
    const u16* __restrict__ A0, const u16* __restrict__ B0, u16* __restrict__ O0,
    const u16* __restrict__ A1, const u16* __restrict__ B1, u16* __restrict__ O1,
    int lda, int ldb, int ldout, int ysplit)
{
  constexpr int KD8 = KC * 4;          // 16B chunks per row
  __shared__ u16 sA[64 * LDK];
  __shared__ u16 sB[64 * LDK];
  const int tid = threadIdx.x;
  const int yy = blockIdx.y;
  const bool sec = yy >= ysplit;
  const u16* A  = sec ? A1 : A0;
  const u16* BT = sec ? B1 : B0;
  u16* out      = sec ? O1 : O0;
  const int c0 = (sec ? yy - ysplit : yy) * 64;
  const int p0 = blockIdx.x * 64;

  #pragma unroll
  for (int it = 0; it < KC; ++it) {
    const int c = it * 256 + tid;
    const int row = c / KD8, k8 = c - row * KD8;
    const int se = row * LDK + (((k8 * 16) ^ ((row & 7) << 4)) >> 1);
    *(uint4*)&sA[se] = *(const uint4*)(A + (size_t)(p0 + row) * lda + k8 * 8);
    *(uint4*)&sB[se] = *(const uint4*)(BT + (size_t)(c0 + row) * ldb + k8 * 8);
  }
  __syncthreads();

  const int lane = tid & 63, wave = tid >> 6;
  const int r0 = wave * 16;
  const int frow = lane & 15;
  const int kbase2 = ((lane >> 4) * 8) * 2;

  bf16x8 af[KC];
  #pragma unroll
  for (int kc = 0; kc < KC; ++kc) {
    const int row = r0 + frow;
    af[kc] = *(const bf16x8*)&sA[row * LDK + (((kc * 64 + kbase2) ^ ((row & 7) << 4)) >> 1)];
  }

  f32x4 acc[4];
  #pragma unroll
  for (int ct = 0; ct < 4; ++ct) acc[ct] = (f32x4){0.f, 0.f, 0.f, 0.f};

  #pragma unroll
  for (int ct = 0; ct < 4; ++ct) {
    const int brow = ct * 16 + frow;
    #pragma unroll
    for (int kc = 0; kc < KC; ++kc) {
      const bf16x8 bfr = *(const bf16x8*)&sB[brow * LDK + (((kc * 64 + kbase2) ^ ((brow & 7) << 4)) >> 1)];
      acc[ct] = __builtin_amdgcn_mfma_f32_16x16x32_bf16(af[kc], bfr, acc[ct], 0, 0, 0);
    }
  }

  const int orow = p0 + r0 + (lane >> 4) * 4;
  #pragma unroll
  for (int ct = 0; ct < 4; ++ct) {
    const int col = c0 + ct * 16 + (lane & 15);
    #pragma unroll
    for (int reg = 0; reg < 4; ++reg)
      out[(size_t)(orow + reg) * ldout + col] = f2bf(acc[ct][reg]);
  }
}

// ---------------- k_rec: 7-step GRU, MFMA recurrence, 16 n / block ------------------
// Whh (bf16 [384][128]) resident in registers; h state in 4KB swizzled LDS.
// Wave w owns gate-tiles {w, w+4, ..., w+20}: i<2 -> r (d-tiles), i in 2..3 -> z, 4..5 -> n.
__global__ __launch_bounds__(256) void k_rec(
    const u16* __restrict__ xg,   // [P][384] bf16, no bias
    const u16* __restrict__ whh,  // [384][128] bf16
    const float* __restrict__ bih, const float* __restrict__ bhh,
    u16* __restrict__ hout)       // [P][128] bf16
{
  __shared__ u16 sH[16 * 128];
  const int tid = threadIdx.x;
  const int lane = tid & 63, wave = tid >> 6;
  const int l15 = lane & 15, lq = lane >> 4;
  const int n0 = blockIdx.x * 16;

  { uint4 z = {0, 0, 0, 0}; *(uint4*)&sH[tid * 8] = z; }

  bf16x8 wf[6][4];
  float binit[6], bxn2[2];
  #pragma unroll
  for (int i = 0; i < 6; ++i) {
    const int g = (wave + i * 4) * 16 + l15;
    #pragma unroll
    for (int kc = 0; kc < 4; ++kc)
      wf[i][kc] = *(const bf16x8*)(whh + (size_t)g * 128 + lq * 8 + kc * 32);
    binit[i] = (i < 4) ? (bih[g] + bhh[g]) : bhh[g];
    if (i >= 4) bxn2[i - 4] = bih[g];
  }
  float hold[2][4] = {{0.f, 0.f, 0.f, 0.f}, {0.f, 0.f, 0.f, 0.f}};
  const size_t rowb = (size_t)(n0 + lq * 4) * 2688;   // *7*384
  __syncthreads();

  for (int w = 0; w < 7; ++w) {
    bf16x8 af[4];
    #pragma unroll
    for (int kc = 0; kc < 4; ++kc) {
      const int byte = l15 * 256 + ((lq * 16 + kc * 64) ^ ((l15 & 7) << 4));
      af[kc] = *(const bf16x8*)((const char*)sH + byte);
    }
    f32x4 acc[6];
    float xn2[2][4];
    #pragma unroll
    for (int i = 0; i < 6; ++i) {
      const int g = (wave + i * 4) * 16 + l15;
      #pragma unroll
      for (int r = 0; r < 4; ++r) {
        const float xvv = bf2f(xg[rowb + (size_t)r * 2688 + w * 384 + g]);
        if (i < 4) acc[i][r] = xvv + binit[i];
        else { acc[i][r] = binit[i]; xn2[i - 4][r] = xvv; }
      }
    }
    #pragma unroll
    for (int i = 0; i < 6; ++i)
      #pragma unroll
      for (int kc = 0; kc < 4; ++kc)
        acc[i] = __builtin_amdgcn_mfma_f32_16x16x32_bf16(af[kc], wf[i][kc], acc[i], 0, 0, 0);

    float hnew[2][4];
    #pragma unroll
    for (int t = 0; t < 2; ++t)
      #pragma unroll
      for (int r = 0; r < 4; ++r) {
        const float rg = sigm(acc[t][r]);
        const float zg = sigm(acc[t + 2][r]);
        const float nn = tanh_fast(xn2[t][r] + bxn2[t] + rg * acc[t + 4][r]);
        hnew[t][r] = (1.f - zg) * nn + zg * hold[t][r];
        hold[t][r] = hnew[t][r];
      }
    __syncthreads();   // all A-frag reads done before state rewrite
    #pragma unroll
    for (int t = 0; t < 2; ++t) {
      const int d = (wave + t * 4) * 16 + l15;
      #pragma unroll
      for (int r = 0; r < 4; ++r) {
        const int n = lq * 4 + r;
        const u16 hb = f2bf(hnew[t][r]);
        *(u16*)((char*)sH + n * 256 + ((d * 2) ^ ((n & 7) << 4))) = hb;
        hout[((size_t)(n0 + n) * 7 + w) * 128 + d] = hb;
      }
    }
    __syncthreads();   // state visible for next step
  }
}

// ---------------- k_rec2: cell chain (lin2 + GRU) + head, MFMA, 16 n / block --------
__global__ __launch_bounds__(256) void k_rec2(
    const u16* __restrict__ xgc,   // [P][384] bf16 (no bias)
    const u16* __restrict__ l2b,   // [P][128] bf16 (W2b@h1, no bias)
    const u16* __restrict__ w2a,   // [128][128] bf16
    const u16* __restrict__ whhc,  // [384][128] bf16
    const u16* __restrict__ hypw,  // [128][128] bf16
    const float* __restrict__ lin2_b, const float* __restrict__ c_bih,
    const float* __restrict__ c_bhh, const float* __restrict__ hyp_b,
    const float* __restrict__ bn_g, const float* __restrict__ bn_be,
    const float* __restrict__ bn_m, const float* __restrict__ bn_v,
    const float* __restrict__ out_W, const float* __restrict__ out_b,
    const float* __restrict__ Y,
    float* __restrict__ outp, float* __restrict__ bloss)
{
  __shared__ u16 sHx[16 * 128];
  __shared__ u16 sT[16 * 128];
  __shared__ float s_red[16][66];
  __shared__ float s_ls[16];
  const int tid = threadIdx.x;
  const int lane = tid & 63, wave = tid >> 6;
  const int l15 = lane & 15, lq = lane >> 4;
  const int n0 = blockIdx.x * 16;

  { uint4 z = {0, 0, 0, 0}; *(uint4*)&sHx[tid * 8] = z; }

  bf16x8 w2f[2][4];
  float b2t[2];
  #pragma unroll
  for (int t = 0; t < 2; ++t) {
    const int d = (wave + t * 4) * 16 + l15;
    #pragma unroll
    for (int kc = 0; kc < 4; ++kc)
      w2f[t][kc] = *(const bf16x8*)(w2a + (size_t)d * 128 + lq * 8 + kc * 32);
    b2t[t] = lin2_b[d];
  }
  bf16x8 wcf[6][4];
  float cbinit[6], cbxn[2];
  #pragma unroll
  for (int i = 0; i < 6; ++i) {
    const int g = (wave + i * 4) * 16 + l15;
    #pragma unroll
    for (int kc = 0; kc < 4; ++kc)
      wcf[i][kc] = *(const bf16x8*)(whhc + (size_t)g * 128 + lq * 8 + kc * 32);
    cbinit[i] = (i < 4) ? (c_bih[g] + c_bhh[g]) : c_bhh[g];
    if (i >= 4) cbxn[i - 4] = c_bih[g];
  }
  const size_t rowb = (size_t)(n0 + lq * 4) * 2688;
  float hx1[2][4];
  __syncthreads();

  for (int w = 0; w < 7; ++w) {
    // ---- round 1: hx1 = tanh(W2a@hx + W2b@h1 + b2) ----
    bf16x8 af[4];
    #pragma unroll
    for (int kc = 0; kc < 4; ++kc) {
      const int byte = l15 * 256 + ((lq * 16 + kc * 64) ^ ((l15 & 7) << 4));
      af[kc] = *(const bf16x8*)((const char*)sHx + byte);
    }
    f32x4 a1[2];
    #pragma unroll
    for (int t = 0; t < 2; ++t) {
      const int d = (wave + t * 4) * 16 + l15;
      #pragma unroll
      for (int r = 0; r < 4; ++r)
        a1[t][r] = bf2f(l2b[((size_t)(n0 + lq * 4 + r) * 7 + w) * 128 + d]) + b2t[t];
    }
    #pragma unroll
    for (int t = 0; t < 2; ++t)
      #pragma unroll
      for (int kc = 0; kc < 4; ++kc)
        a1[t] = __builtin_amdgcn_mfma_f32_16x16x32_bf16(af[kc], w2f[t][kc], a1[t], 0, 0, 0);
    #pragma unroll
    for (int t = 0; t < 2; ++t)
      #pragma unroll
      for (int r = 0; r < 4; ++r) hx1[t][r] = tanh_fast(a1[t][r]);
    __syncthreads();   // sHx reads done
    #pragma unroll
    for (int t = 0; t < 2; ++t) {
      const int d = (wave + t * 4) * 16 + l15;
      #pragma unroll
      for (int r = 0; r < 4; ++r) {
        const int n = lq * 4 + r;
        *(u16*)((char*)sT + n * 256 + ((d * 2) ^ ((n & 7) << 4))) = f2bf(hx1[t][r]);
      }
    }
    __syncthreads();   // sT ready

    // ---- round 2: cell GRU, state = hx1 ----
    bf16x8 at[4];
    #pragma unroll
    for (int kc = 0; kc < 4; ++kc) {
      const int byte = l15 * 256 + ((lq * 16 + kc * 64) ^ ((l15 & 7) << 4));
      at[kc] = *(const bf16x8*)((const char*)sT + byte);
    }
    f32x4 a2[6];
    float xn2[2][4];
    #pragma unroll
    for (int i = 0; i < 6; ++i) {
      const int g = (wave + i * 4) * 16 + l15;
      #pragma unroll
      for (int r = 0; r < 4; ++r) {
        const float xvv = bf2f(xgc[rowb + (size_t)r * 2688 + w * 384 + g]);
        if (i < 4) a2[i][r] = xvv + cbinit[i];
        else { a2[i][r] = cbinit[i]; xn2[i - 4][r] = xvv; }
      }
    }
    #pragma unroll
    for (int i = 0; i < 6; ++i)
      #pragma unroll
      for (int kc = 0; kc < 4; ++kc)
        a2[i] = __builtin_amdgcn_mfma_f32_16x16x32_bf16(at[kc], wcf[i][kc], a2[i], 0, 0, 0);
    #pragma unroll
    for (int t = 0; t < 2; ++t) {
      const int d = (wave + t * 4) * 16 + l15;
      #pragma unroll
      for (int r = 0; r < 4; ++r) {
        const float rg = sigm(a2[t][r]);
        const float zg = sigm(a2[t + 2][r]);
        const float nn = tanh_fast(xn2[t][r] + cbxn[t] + rg * a2[t + 4][r]);
        const float hnew = (1.f - zg) * nn + zg * hx1[t][r];
        const int n = lq * 4 + r;
        *(u16*)((char*)sHx + n * 256 + ((d * 2) ^ ((n & 7) << 4))) = f2bf(hnew);
      }
    }
    __syncthreads();   // sHx visible (and all sT reads done before next rewrite)
  }

  // ---- head: relu(BN(hyp_W@hx + hyp_b)) -> y -> sigmoid + loss partial ----
  bf16x8 af[4];
  #pragma unroll
  for (int kc = 0; kc < 4; ++kc) {
    const int byte = l15 * 256 + ((lq * 16 + kc * 64) ^ ((l15 & 7) << 4));
    af[kc] = *(const bf16x8*)((const char*)sHx + byte);
  }
  f32x4 ah[2];
  float sc[2], mu[2], be[2], ow[2];
  #pragma unroll
  for (int t = 0; t < 2; ++t) {
    const int q = (wave + t * 4) * 16 + l15;
    #pragma unroll
    for (int r = 0; r < 4; ++r) ah[t][r] = hyp_b[q];
    sc[t] = rsqrtf(bn_v[q] + 1e-5f) * bn_g[q];
    mu[t] = bn_m[q]; be[t] = bn_be[q]; ow[t] = out_W[q];
  }
  {
    bf16x8 hf;
    #pragma unroll
    for (int t = 0; t < 2; ++t) {
      const int q = (wave + t * 4) * 16 + l15;
      #pragma unroll
      for (int kc = 0; kc < 4; ++kc) {
        hf = *(const bf16x8*)(hypw + (size_t)q * 128 + lq * 8 + kc * 32);
        ah[t] = __builtin_amdgcn_mfma_f32_16x16x32_bf16(af[kc], hf, ah[t], 0, 0, 0);
      }
    }
  }
  float part[4] = {0.f, 0.f, 0.f, 0.f};
  #pragma unroll
  for (int t = 0; t < 2; ++t)
    #pragma unroll
    for (int r = 0; r < 4; ++r) {
      const float v = (ah[t][r] - mu[t]) * sc[t] + be[t];
      part[r] += ow[t] * fmaxf(v, 0.f);
    }
  #pragma unroll
  for (int r = 0; r < 4; ++r) s_red[lq * 4 + r][wave * 16 + l15] = part[r];
  __syncthreads();
  if (tid < 16) {
    const int n = tid;
    float y = out_b[0];
    #pragma unroll 8
    for (int c = 0; c < 64; ++c) y += s_red[n][c];
    outp[1 + n0 + n] = 1.f / (1.f + __expf(-y));
    const float tY = Y[(size_t)(n0 + n) * 33];
    s_ls[n] = fmaxf(y, 0.f) - y * tY + log1pf(__expf(-fabsf(y)));
  }
  __syncthreads();
  if (tid == 0) {
    float s = 0.f;
    #pragma unroll
    for (int j = 0; j < 16; ++j) s += s_ls[j];
    bloss[blockIdx.x] = s;
  }
}

// ---------------- K3: loss reduction (256 partials) ----------------
__global__ __launch_bounds__(256) void k3_loss(const float* __restrict__ bloss,
                                               float* __restrict__ out)
{
  __shared__ float s[256];
  s[threadIdx.x] = bloss[threadIdx.x];
  __syncthreads();
  for (int off = 128; off > 0; off >>= 1) {
    if (threadIdx.x < off) s[threadIdx.x] += s[threadIdx.x + off];
    __syncthreads();
  }
  if (threadIdx.x == 0) out[0] = s[0] * (1.0f / 4096.0f);
}

extern "C" void kernel_launch(void* const* d_in, const int* in_sizes, int n_in,
                              void* d_out, int out_size, void* d_ws, size_t ws_size,
                              hipStream_t stream) {
  const float* X       = (const float*)d_in[0];
  const float* Y       = (const float*)d_in[1];
  const float* C       = (const float*)d_in[2];
  const float* msg_W   = (const float*)d_in[3];
  const float* msg_b   = (const float*)d_in[4];
  const float* g0_Wih  = (const float*)d_in[5];
  const float* g0_Whh  = (const float*)d_in[6];
  const float* g0_bih  = (const float*)d_in[7];
  const float* g0_bhh  = (const float*)d_in[8];
  const float* g1_Wih  = (const float*)d_in[9];
  const float* g1_Whh  = (const float*)d_in[10];
  const float* g1_bih  = (const float*)d_in[11];
  const float* g1_bhh  = (const float*)d_in[12];
  const float* lin_W   = (const float*)d_in[13];
  const float* lin_b   = (const float*)d_in[14];
  const float* lin2_W  = (const float*)d_in[15];
  const float* lin2_b  = (const float*)d_in[16];
  const float* c_Wih   = (const float*)d_in[17];
  const float* c_Whh   = (const float*)d_in[18];
  const float* c_bih   = (const float*)d_in[19];
  const float* c_bhh   = (const float*)d_in[20];
  const float* hyp_W   = (const float*)d_in[21];
  const float* hyp_b   = (const float*)d_in[22];
  const float* bn_g    = (const float*)d_in[23];
  const float* bn_be   = (const float*)d_in[24];
  const float* bn_m    = (const float*)d_in[25];
  const float* bn_v    = (const float*)d_in[26];
  const float* out_W   = (const float*)d_in[27];
  const float* out_b   = (const float*)d_in[28];

  const size_t P = NPAIR;
  u16* xw    = (u16*)d_ws;
  u16* tx    = xw    + P * 288;
  u16* hmsg  = tx    + P * 288;
  u16* hself = hmsg  + P * 128;
  u16* h0b   = hself + P * 128;
  u16* h1b   = h0b   + P * 128;
  u16* xg0   = h1b   + P * 128;
  u16* xgc   = xg0   + P * 384;
  u16* xg1   = xgc   + P * 384;
  u16* l2b   = xg1   + P * 384;
  u16* wbase = l2b   + P * 128;
  u16* bt_msg = wbase;            // [128][288]
  u16* bt_lin = wbase + 36864;    // [128][288]
  u16* g0w    = wbase + 73728;    // [384][128]
  u16* g1w    = wbase + 122880;
  u16* cw     = wbase + 172032;
  u16* l2w    = wbase + 221184;   // [128][128]
  u16* w2a    = wbase + 237568;   // [128][128]
  u16* whh0   = wbase + 253952;   // [384][128]
  u16* whh1   = wbase + 303104;
  u16* whhc   = wbase + 352256;
  u16* hypw   = wbase + 401408;   // [128][128]
  float* bloss = (float*)(wbase + 417792);

  float* out = (float*)d_out;

  k_prep_all<<<dim3(192, 11), 256, 0, stream>>>(msg_W, msg_b, lin_W, lin_b,
      g0_Wih, g1_Wih, c_Wih, lin2_W, g0_Whh, g1_Whh, c_Whh, hyp_W, wbase);

  k1p1<<<NPAIR / 16, 256, 0, stream>>>(X, C, xw, tx);

  k_gemm2<9, 320><<<dim3(448, 4), 256, 0, stream>>>(
      xw, bt_msg, hmsg, tx, bt_lin, hself, 288, 288, 128, 2);
  k_gemm2<4, 128><<<dim3(448, 12), 256, 0, stream>>>(
      hmsg, g0w, xg0, hself, cw, xgc, 128, 128, 384, 6);
  k_rec<<<256, 256, 0, stream>>>(xg0, whh0, g0_bih, g0_bhh, h0b);
  k_gemm2<4, 128><<<dim3(448, 6), 256, 0, stream>>>(
      h0b, g1w, xg1, h0b, g1w, xg1, 128, 128, 384, 6);
  k_rec<<<256, 256, 0, stream>>>(xg1, whh1, g1_bih, g1_bhh, h1b);
  k_gemm2<4, 128><<<dim3(448, 2), 256, 0, stream>>>(
      h1b, l2w, l2b, h1b, l2w, l2b, 128, 128, 128, 2);
  k_rec2<<<256, 256, 0, stream>>>(xgc, l2b, w2a, whhc, hypw,
      lin2_b, c_bih, c_bhh, hyp_b, bn_g, bn_be, bn_m, bn_v, out_W, out_b,
      Y, out, bloss);
  k3_loss<<<1, 256, 0, stream>>>(bloss, out);
}

// Round 5
// 252.165 us; speedup vs baseline: 5.5107x; 1.4134x over previous
//
#include <hip/hip_runtime.h>
#include <math.h>

#define N_    4096
#define NPAIR (N_ * 7)   // 28672

typedef unsigned short u16;
typedef __attribute__((ext_vector_type(8))) short bf16x8;
typedef __attribute__((ext_vector_type(4))) float f32x4;

__device__ __forceinline__ float sigm(float x) { return 1.0f / (1.0f + __expf(-x)); }
__device__ __forceinline__ float tanh_fast(float x) { return 2.0f / (1.0f + __expf(-2.0f * x)) - 1.0f; }
__device__ __forceinline__ float bf2f(u16 u) { return __uint_as_float(((unsigned)u) << 16); }
__device__ __forceinline__ u16 f2bf(float f) {
  unsigned u = __float_as_uint(f);
  return (u16)((u + 0x7FFFu + ((u >> 16) & 1u)) >> 16);
}
__device__ __forceinline__ f32x4 mfma16(bf16x8 a, bf16x8 b, f32x4 c) {
  return __builtin_amdgcn_mfma_f32_16x16x32_bf16(a, b, c, 0, 0, 0);
}

// ---------------- k_prep_all: all weight fp32->bf16 conversions, one launch --------
__global__ __launch_bounds__(256) void k_prep_all(
    const float* __restrict__ msg_W, const float* __restrict__ lin_W,
    const float* __restrict__ g0_Wih, const float* __restrict__ g1_Wih,
    const float* __restrict__ c_Wih, const float* __restrict__ lin2_W,
    const float* __restrict__ g0_Whh, const float* __restrict__ g1_Whh,
    const float* __restrict__ c_Whh, const float* __restrict__ hyp_W,
    u16* __restrict__ wbase)
{
  const int task = blockIdx.y;
  const int i = blockIdx.x * 256 + threadIdx.x;
  int R, KD, stride, koff, doff;
  const float* src;
  switch (task) {
    case 0:  R=128; KD=256; stride=256; koff=0;   src=msg_W;  doff=0;      break;
    case 1:  R=128; KD=256; stride=256; koff=0;   src=lin_W;  doff=32768;  break;
    case 2:  R=384; KD=128; stride=128; koff=0;   src=g0_Wih; doff=65536;  break;
    case 3:  R=384; KD=128; stride=128; koff=0;   src=g1_Wih; doff=114688; break;
    case 4:  R=384; KD=128; stride=128; koff=0;   src=c_Wih;  doff=163840; break;
    case 5:  R=128; KD=128; stride=256; koff=128; src=lin2_W; doff=212992; break;  // l2w = lin2_W[:,128:]
    case 6:  R=128; KD=128; stride=256; koff=0;   src=lin2_W; doff=229376; break;  // w2a = lin2_W[:,:128]
    case 7:  R=384; KD=128; stride=128; koff=0;   src=g0_Whh; doff=245760; break;
    case 8:  R=384; KD=128; stride=128; koff=0;   src=g1_Whh; doff=294912; break;
    case 9:  R=384; KD=128; stride=128; koff=0;   src=c_Whh;  doff=344064; break;
    default: R=128; KD=128; stride=128; koff=0;   src=hyp_W;  doff=393216; break;
  }
  if (i >= R * KD) return;
  const int r = i / KD, k = i - r * KD;
  wbase[doff + i] = f2bf(src[(size_t)r * stride + koff + k]);
}

// ---------------- k1_fused: stream X + weighted reduce + msg/lin MFMA GEMM ----------
// block = 16 pairs; phase1 fills swizzled 16x256 bf16 LDS tiles; phase2 = MFMA.
__global__ __launch_bounds__(256) void k1_fused(
    const float* __restrict__ X, const float* __restrict__ C,
    const u16* __restrict__ msgw, const u16* __restrict__ linw,   // [128][256] bf16
    const float* __restrict__ msg_b, const float* __restrict__ lin_b,
    u16* __restrict__ hmsg, u16* __restrict__ hself)
{
  __shared__ u16 sXW[16 * 256];
  __shared__ u16 sTX[16 * 256];
  __shared__ float s_ps[16];
  const int tid = threadIdx.x, wave = tid >> 6, lane = tid & 63;
  const int p0 = blockIdx.x * 16;

  for (int q = 0; q < 4; ++q) {
    const int lp = wave * 4 + q;
    const int p = p0 + lp;
    const int n = p / 7, w = p - n * 7;
    const float* xb = X + ((size_t)(n * 33 + 1) * 7 + w) * 256 + lane * 4;
    const float* cb = C + (size_t)(n * 33 + 1) * 7 + w;
    float4 acc = make_float4(0.f, 0.f, 0.f, 0.f);
    float ps = 0.f;
    #pragma unroll 4
    for (int m = 0; m < 32; ++m) {
      const float c = cb[m * 7];
      const float4 x4 = *(const float4*)(xb + (size_t)m * 1792);
      acc.x += c * x4.x; acc.y += c * x4.y; acc.z += c * x4.z; acc.w += c * x4.w;
      ps += c;
    }
    const int sb = lp * 512 + ((lane * 8) ^ ((lp & 7) << 4));
    ushort4 o = {f2bf(acc.x), f2bf(acc.y), f2bf(acc.z), f2bf(acc.w)};
    *(ushort4*)((char*)sXW + sb) = o;
    const float4 t4 = *(const float4*)(X + ((size_t)(n * 33) * 7 + w) * 256 + lane * 4);
    ushort4 ot = {f2bf(t4.x), f2bf(t4.y), f2bf(t4.z), f2bf(t4.w)};
    *(ushort4*)((char*)sTX + sb) = ot;
    if (lane == 0) s_ps[lp] = ps;
  }
  __syncthreads();

  const int l15 = lane & 15, lq = lane >> 4;
  bf16x8 ax[8], at[8];
  #pragma unroll
  for (int kc = 0; kc < 8; ++kc) {
    const int off = l15 * 512 + ((lq * 16 + kc * 64) ^ ((l15 & 7) << 4));
    ax[kc] = *(const bf16x8*)((const char*)sXW + off);
    at[kc] = *(const bf16x8*)((const char*)sTX + off);
  }
  float psr[4];
  #pragma unroll
  for (int r = 0; r < 4; ++r) psr[r] = s_ps[lq * 4 + r];

  #pragma unroll
  for (int ct = 0; ct < 2; ++ct) {
    const int col = (wave + ct * 4) * 16 + l15;
    f32x4 am = {0.f, 0.f, 0.f, 0.f}, as = {0.f, 0.f, 0.f, 0.f};
    #pragma unroll
    for (int kc = 0; kc < 8; ++kc) {
      const bf16x8 bm = *(const bf16x8*)(msgw + (size_t)col * 256 + lq * 8 + kc * 32);
      const bf16x8 bl = *(const bf16x8*)(linw + (size_t)col * 256 + lq * 8 + kc * 32);
      am = mfma16(ax[kc], bm, am);
      as = mfma16(at[kc], bl, as);
    }
    const float mb = msg_b[col], lb = lin_b[col];
    #pragma unroll
    for (int r = 0; r < 4; ++r) {
      const int p = p0 + lq * 4 + r;
      hmsg[(size_t)p * 128 + col]  = f2bf(am[r] + mb * psr[r]);
      hself[(size_t)p * 128 + col] = f2bf(as[r] + lb);
    }
  }
}

// ---------------- k_chain: gru0 -> gru1 -> (lin2+cell) -> head, 16 n / block --------
__device__ __forceinline__ void stage16(u16* __restrict__ dst,
                                        const u16* __restrict__ src,
                                        int n0, int tid)
{
  #pragma unroll
  for (int it = 0; it < 7; ++it) {
    const int chunk = it * 256 + tid;
    const int w = chunk >> 8, rem = chunk & 255;
    const int n = rem >> 4, d0 = (rem & 15) * 8;
    const uint4 v = *(const uint4*)(src + ((size_t)(n0 + n) * 7 + w) * 128 + d0);
    *(uint4*)((char*)dst + w * 4096 + n * 256 + ((d0 * 2) ^ ((n & 7) << 4))) = v;
  }
}

__device__ __forceinline__ void gru_stage(
    u16* __restrict__ sin, u16* __restrict__ sout,
    const u16* __restrict__ wih, const u16* __restrict__ whh,
    const float* __restrict__ bih, const float* __restrict__ bhh,
    int wave, int l15, int lq)
{
  bf16x8 wi[6][4], wh[6][4];
  float binit[6], bxn[2];
  #pragma unroll
  for (int i = 0; i < 6; ++i) {
    const int g = (wave + i * 4) * 16 + l15;
    #pragma unroll
    for (int kc = 0; kc < 4; ++kc) {
      wi[i][kc] = *(const bf16x8*)(wih + (size_t)g * 128 + lq * 8 + kc * 32);
      wh[i][kc] = *(const bf16x8*)(whh + (size_t)g * 128 + lq * 8 + kc * 32);
    }
    binit[i] = (i < 4) ? (bih[g] + bhh[g]) : bhh[g];
    if (i >= 4) bxn[i - 4] = bih[g];
  }
  float hold[2][4] = {{0.f, 0.f, 0.f, 0.f}, {0.f, 0.f, 0.f, 0.f}};

  for (int w = 0; w < 7; ++w) {
    bf16x8 afx[4], afh[4];
    #pragma unroll
    for (int kc = 0; kc < 4; ++kc) {
      const int off = l15 * 256 + ((lq * 16 + kc * 64) ^ ((l15 & 7) << 4));
      afx[kc] = *(const bf16x8*)((const char*)sin + w * 4096 + off);
      if (w) afh[kc] = *(const bf16x8*)((const char*)sout + (w - 1) * 4096 + off);
    }
    f32x4 acc[6], accx[2];
    #pragma unroll
    for (int i = 0; i < 6; ++i) acc[i] = (f32x4){binit[i], binit[i], binit[i], binit[i]};
    #pragma unroll
    for (int t = 0; t < 2; ++t) accx[t] = (f32x4){bxn[t], bxn[t], bxn[t], bxn[t]};

    #pragma unroll
    for (int i = 0; i < 6; ++i) {
      #pragma unroll
      for (int kc = 0; kc < 4; ++kc) {
        if (i < 4) acc[i] = mfma16(afx[kc], wi[i][kc], acc[i]);
        else       accx[i - 4] = mfma16(afx[kc], wi[i][kc], accx[i - 4]);
        if (w) acc[i] = mfma16(afh[kc], wh[i][kc], acc[i]);
      }
    }
    #pragma unroll
    for (int t = 0; t < 2; ++t) {
      const int d = (wave + t * 4) * 16 + l15;
      #pragma unroll
      for (int r = 0; r < 4; ++r) {
        const float rg = sigm(acc[t][r]);
        const float zg = sigm(acc[t + 2][r]);
        const float nn = tanh_fast(accx[t][r] + rg * acc[t + 4][r]);
        const float hv = (1.f - zg) * nn + zg * hold[t][r];
        hold[t][r] = hv;
        const int n = lq * 4 + r;
        *(u16*)((char*)sout + w * 4096 + n * 256 + ((d * 2) ^ ((n & 7) << 4))) = f2bf(hv);
      }
    }
    __syncthreads();
  }
}

__global__ __launch_bounds__(256, 1) void k_chain(
    const u16* __restrict__ hmsg, const u16* __restrict__ hself,
    const u16* __restrict__ wbase,
    const float* __restrict__ g0_bih, const float* __restrict__ g0_bhh,
    const float* __restrict__ g1_bih, const float* __restrict__ g1_bhh,
    const float* __restrict__ lin2_b,
    const float* __restrict__ c_bih, const float* __restrict__ c_bhh,
    const float* __restrict__ hyp_b,
    const float* __restrict__ bn_g, const float* __restrict__ bn_be,
    const float* __restrict__ bn_m, const float* __restrict__ bn_v,
    const float* __restrict__ out_W, const float* __restrict__ out_b,
    const float* __restrict__ Y,
    float* __restrict__ outp, float* __restrict__ bloss)
{
  __shared__ u16 sA[7 * 2048];   // 28 KB
  __shared__ u16 sB[7 * 2048];   // 28 KB
  __shared__ u16 sC[2048];       // 4 KB
  __shared__ u16 sD[2048];       // 4 KB
  __shared__ float s_red[16][66];
  __shared__ float s_ls[16];

  const int tid = threadIdx.x;
  const int lane = tid & 63, wave = tid >> 6;
  const int l15 = lane & 15, lq = lane >> 4;
  const int n0 = blockIdx.x * 16;

  const u16* g0wih = wbase + 65536;
  const u16* g1wih = wbase + 114688;
  const u16* cwih  = wbase + 163840;
  const u16* l2w   = wbase + 212992;
  const u16* w2a   = wbase + 229376;
  const u16* whh0  = wbase + 245760;
  const u16* whh1  = wbase + 294912;
  const u16* whhc  = wbase + 344064;
  const u16* hypw  = wbase + 393216;

  stage16(sA, hmsg, n0, tid);
  __syncthreads();

  gru_stage(sA, sB, g0wih, whh0, g0_bih, g0_bhh, wave, l15, lq);  // h0 -> sB
  gru_stage(sB, sA, g1wih, whh1, g1_bih, g1_bhh, wave, l15, lq);  // h1 -> sA

  stage16(sB, hself, n0, tid);   // h0 dead; sB <- hself
  __syncthreads();

  // ---- cell chain: hx1 = tanh(w2a@hx + l2w@h1 + b2); hx = GRU_c(Wc@hself, hx1) ----
  {
    bf16x8 lw[2][4], wa[2][4], wi[6][4], wh[6][4];
    float b2[2], cbin[6], cbxn[2];
    #pragma unroll
    for (int t = 0; t < 2; ++t) {
      const int d = (wave + t * 4) * 16 + l15;
      #pragma unroll
      for (int kc = 0; kc < 4; ++kc) {
        lw[t][kc] = *(const bf16x8*)(l2w + (size_t)d * 128 + lq * 8 + kc * 32);
        wa[t][kc] = *(const bf16x8*)(w2a + (size_t)d * 128 + lq * 8 + kc * 32);
      }
      b2[t] = lin2_b[d];
    }
    #pragma unroll
    for (int i = 0; i < 6; ++i) {
      const int g = (wave + i * 4) * 16 + l15;
      #pragma unroll
      for (int kc = 0; kc < 4; ++kc) {
        wi[i][kc] = *(const bf16x8*)(cwih + (size_t)g * 128 + lq * 8 + kc * 32);
        wh[i][kc] = *(const bf16x8*)(whhc + (size_t)g * 128 + lq * 8 + kc * 32);
      }
      cbin[i] = (i < 4) ? (c_bih[g] + c_bhh[g]) : c_bhh[g];
      if (i >= 4) cbxn[i - 4] = c_bih[g];
    }

    for (int w = 0; w < 7; ++w) {
      // round 1: hx1
      bf16x8 af1[4], afx_[4];
      #pragma unroll
      for (int kc = 0; kc < 4; ++kc) {
        const int off = l15 * 256 + ((lq * 16 + kc * 64) ^ ((l15 & 7) << 4));
        af1[kc] = *(const bf16x8*)((const char*)sA + w * 4096 + off);
        if (w) afx_[kc] = *(const bf16x8*)((const char*)sD + off);
      }
      f32x4 a1[2];
      #pragma unroll
      for (int t = 0; t < 2; ++t) a1[t] = (f32x4){b2[t], b2[t], b2[t], b2[t]};
      #pragma unroll
      for (int t = 0; t < 2; ++t)
        #pragma unroll
        for (int kc = 0; kc < 4; ++kc) {
          a1[t] = mfma16(af1[kc], lw[t][kc], a1[t]);
          if (w) a1[t] = mfma16(afx_[kc], wa[t][kc], a1[t]);
        }
      float hx1[2][4];
      #pragma unroll
      for (int t = 0; t < 2; ++t) {
        const int d = (wave + t * 4) * 16 + l15;
        #pragma unroll
        for (int r = 0; r < 4; ++r) {
          hx1[t][r] = tanh_fast(a1[t][r]);
          const int n = lq * 4 + r;
          *(u16*)((char*)sC + n * 256 + ((d * 2) ^ ((n & 7) << 4))) = f2bf(hx1[t][r]);
        }
      }
      __syncthreads();

      // round 2: cell GRU
      bf16x8 afs[4], aft[4];
      #pragma unroll
      for (int kc = 0; kc < 4; ++kc) {
        const int off = l15 * 256 + ((lq * 16 + kc * 64) ^ ((l15 & 7) << 4));
        afs[kc] = *(const bf16x8*)((const char*)sB + w * 4096 + off);
        aft[kc] = *(const bf16x8*)((const char*)sC + off);
      }
      f32x4 acc[6], accx[2];
      #pragma unroll
      for (int i = 0; i < 6; ++i) acc[i] = (f32x4){cbin[i], cbin[i], cbin[i], cbin[i]};
      #pragma unroll
      for (int t = 0; t < 2; ++t) accx[t] = (f32x4){cbxn[t], cbxn[t], cbxn[t], cbxn[t]};
      #pragma unroll
      for (int i = 0; i < 6; ++i)
        #pragma unroll
        for (int kc = 0; kc < 4; ++kc) {
          if (i < 4) acc[i] = mfma16(afs[kc], wi[i][kc], acc[i]);
          else       accx[i - 4] = mfma16(afs[kc], wi[i][kc], accx[i - 4]);
          acc[i] = mfma16(aft[kc], wh[i][kc], acc[i]);
        }
      #pragma unroll
      for (int t = 0; t < 2; ++t) {
        const int d = (wave + t * 4) * 16 + l15;
        #pragma unroll
        for (int r = 0; r < 4; ++r) {
          const float rg = sigm(acc[t][r]);
          const float zg = sigm(acc[t + 2][r]);
          const float nn = tanh_fast(accx[t][r] + rg * acc[t + 4][r]);
          const float hv = (1.f - zg) * nn + zg * hx1[t][r];
          const int n = lq * 4 + r;
          *(u16*)((char*)sD + n * 256 + ((d * 2) ^ ((n & 7) << 4))) = f2bf(hv);
        }
      }
      __syncthreads();
    }
  }

  // ---- head: relu(BN(hyp_W@hx + hyp_b)) -> y -> sigmoid + loss partial ----
  {
    bf16x8 af[4];
    #pragma unroll
    for (int kc = 0; kc < 4; ++kc) {
      const int off = l15 * 256 + ((lq * 16 + kc * 64) ^ ((l15 & 7) << 4));
      af[kc] = *(const bf16x8*)((const char*)sD + off);
    }
    f32x4 ah[2];
    float sc[2], mu[2], be[2], ow[2];
    #pragma unroll
    for (int t = 0; t < 2; ++t) {
      const int q = (wave + t * 4) * 16 + l15;
      const float hb = hyp_b[q];
      ah[t] = (f32x4){hb, hb, hb, hb};
      sc[t] = rsqrtf(bn_v[q] + 1e-5f) * bn_g[q];
      mu[t] = bn_m[q]; be[t] = bn_be[q]; ow[t] = out_W[q];
      #pragma unroll
      for (int kc = 0; kc < 4; ++kc) {
        const bf16x8 hf = *(const bf16x8*)(hypw + (size_t)q * 128 + lq * 8 + kc * 32);
        ah[t] = mfma16(af[kc], hf, ah[t]);
      }
    }
    float part[4] = {0.f, 0.f, 0.f, 0.f};
    #pragma unroll
    for (int t = 0; t < 2; ++t)
      #pragma unroll
      for (int r = 0; r < 4; ++r) {
        const float v = (ah[t][r] - mu[t]) * sc[t] + be[t];
        part[r] += ow[t] * fmaxf(v, 0.f);
      }
    #pragma unroll
    for (int r = 0; r < 4; ++r) s_red[lq * 4 + r][wave * 16 + l15] = part[r];
  }
  __syncthreads();
  if (tid < 16) {
    const int n = tid;
    float y = out_b[0];
    #pragma unroll 8
    for (int c = 0; c < 64; ++c) y += s_red[n][c];
    outp[1 + n0 + n] = 1.f / (1.f + __expf(-y));
    const float tY = Y[(size_t)(n0 + n) * 33];
    s_ls[n] = fmaxf(y, 0.f) - y * tY + log1pf(__expf(-fabsf(y)));
  }
  __syncthreads();
  if (tid == 0) {
    float s = 0.f;
    #pragma unroll
    for (int j = 0; j < 16; ++j) s += s_ls[j];
    bloss[blockIdx.x] = s;
  }
}

// ---------------- K3: loss reduction (256 partials) ----------------
__global__ __launch_bounds__(256) void k3_loss(const float* __restrict__ bloss,
                                               float* __restrict__ out)
{
  __shared__ float s[256];
  s[threadIdx.x] = bloss[threadIdx.x];
  __syncthreads();
  for (int off = 128; off > 0; off >>= 1) {
    if (threadIdx.x < off) s[threadIdx.x] += s[threadIdx.x + off];
    __syncthreads();
  }
  if (threadIdx.x == 0) out[0] = s[0] * (1.0f / 4096.0f);
}

extern "C" void kernel_launch(void* const* d_in, const int* in_sizes, int n_in,
                              void* d_out, int out_size, void* d_ws, size_t ws_size,
                              hipStream_t stream) {
  const float* X       = (const float*)d_in[0];
  const float* Y       = (const float*)d_in[1];
  const float* C       = (const float*)d_in[2];
  const float* msg_W   = (const float*)d_in[3];
  const float* msg_b   = (const float*)d_in[4];
  const float* g0_Wih  = (const float*)d_in[5];
  const float* g0_Whh  = (const float*)d_in[6];
  const float* g0_bih  = (const float*)d_in[7];
  const float* g0_bhh  = (const float*)d_in[8];
  const float* g1_Wih  = (const float*)d_in[9];
  const float* g1_Whh  = (const float*)d_in[10];
  const float* g1_bih  = (const float*)d_in[11];
  const float* g1_bhh  = (const float*)d_in[12];
  const float* lin_W   = (const float*)d_in[13];
  const float* lin_b   = (const float*)d_in[14];
  const float* lin2_W  = (const float*)d_in[15];
  const float* lin2_b  = (const float*)d_in[16];
  const float* c_Wih   = (const float*)d_in[17];
  const float* c_Whh   = (const float*)d_in[18];
  const float* c_bih   = (const float*)d_in[19];
  const float* c_bhh   = (const float*)d_in[20];
  const float* hyp_W   = (const float*)d_in[21];
  const float* hyp_b   = (const float*)d_in[22];
  const float* bn_g    = (const float*)d_in[23];
  const float* bn_be   = (const float*)d_in[24];
  const float* bn_m    = (const float*)d_in[25];
  const float* bn_v    = (const float*)d_in[26];
  const float* out_W   = (const float*)d_in[27];
  const float* out_b   = (const float*)d_in[28];

  const size_t P = NPAIR;
  u16* hmsg  = (u16*)d_ws;
  u16* hself = hmsg  + P * 128;
  u16* wbase = hself + P * 128;
  float* bloss = (float*)(wbase + 409600);

  float* out = (float*)d_out;

  k_prep_all<<<dim3(192, 11), 256, 0, stream>>>(msg_W, lin_W, g0_Wih, g1_Wih,
      c_Wih, lin2_W, g0_Whh, g1_Whh, c_Whh, hyp_W, wbase);

  k1_fused<<<NPAIR / 16, 256, 0, stream>>>(X, C, wbase, wbase + 32768,
      msg_b, lin_b, hmsg, hself);

  k_chain<<<N_ / 16, 256, 0, stream>>>(hmsg, hself, wbase,
      g0_bih, g0_bhh, g1_bih, g1_bhh, lin2_b, c_bih, c_bhh,
      hyp_b, bn_g, bn_be, bn_m, bn_v, out_W, out_b, Y, out, bloss);

  k3_loss<<<1, 256, 0, stream>>>(bloss, out);
}